// Round 9
// baseline (475.636 us; speedup 1.0000x reference)
//
#include <hip/hip_runtime.h>

typedef _Float16 f16;
typedef _Float16 f16x4 __attribute__((ext_vector_type(4)));
typedef _Float16 f16x8 __attribute__((ext_vector_type(8)));
typedef float    f32x4 __attribute__((ext_vector_type(4)));
typedef float    fv2   __attribute__((ext_vector_type(2)));

__device__ __forceinline__ float4 ld4h(const f16* p) {
  f16x4 t = *(const f16x4*)p;
  return make_float4((float)t[0], (float)t[1], (float)t[2], (float)t[3]);
}

__device__ __forceinline__ float4 dec_fp8x4(unsigned u) {
  fv2 lo = __builtin_amdgcn_cvt_pk_f32_fp8(u, false);
  fv2 hi = __builtin_amdgcn_cvt_pk_f32_fp8(u, true);
  return make_float4(lo[0], lo[1], hi[0], hi[1]);
}

__device__ __forceinline__ unsigned enc_fp8x4(float a, float b, float c, float d) {
  unsigned v = 0;
  v = __builtin_amdgcn_cvt_pk_fp8_f32(a, b, v, false);
  v = __builtin_amdgcn_cvt_pk_fp8_f32(c, d, v, true);
  return v;
}

__device__ __forceinline__ f16x8 as_h8(uint4 u) {
  union { uint4 u4; f16x8 h; } c; c.u4 = u; return c.h;
}

__device__ __forceinline__ void gld_lds16(const void* g, void* l) {
  __builtin_amdgcn_global_load_lds(
      (const __attribute__((address_space(1))) unsigned*)g,
      (__attribute__((address_space(3))) unsigned*)l, 16, 0, 0);
}

__device__ __forceinline__ int cell_of(const float* coords, int i) {
  int cx = (int)(coords[2 * i] * 0.02f);
  int cy = (int)(coords[2 * i + 1] * 0.02f);
  cx = cx < 0 ? 0 : (cx > 19 ? 19 : cx);
  cy = cy < 0 ? 0 : (cy > 19 ? 19 : cy);
  return cy * 20 + cx;
}

// ===================== prep: cast (blocks 0..2047) + enc tables (2048..2066) + hist (2067..) =====
// wqvk layout per scale: rows [0:256)=q, [256:512)=v, [512:768)=k
__global__ __launch_bounds__(256) void prep_kernel(
    const float* __restrict__ x, const float* __restrict__ Wq, const float* __restrict__ Wk,
    const float* __restrict__ Wv, const float* __restrict__ Wd2,
    f16* __restrict__ x_h, unsigned* __restrict__ x8, f16* __restrict__ wqvk,
    f16* __restrict__ wd2h,
    const float* __restrict__ dist_emb, const float* __restrict__ dir_emb,
    const float* __restrict__ Wsp1, const float* __restrict__ bsp1,
    const float* __restrict__ Wsp2, const float* __restrict__ bsp2,
    float* __restrict__ enc_tab,
    const int* __restrict__ eidx, const float* __restrict__ coords,
    int* deg_i, int* indeg_i, int* cellcnt, int E, int N)
{
  const int b = blockIdx.x;
  if (b < 2048) {
    // ---- cast ----
    const int n0 = N * 64;
    const int total = n0 + 147456 + 24576;
    for (int i = b * 256 + threadIdx.x; i < total; i += 2048 * 256) {
      int k = i;
      if (k < n0) {
        float4 v = ((const float4*)x)[k];
        f16x4 o; o[0] = (f16)v.x; o[1] = (f16)v.y; o[2] = (f16)v.z; o[3] = (f16)v.w;
        ((f16x4*)x_h)[k] = o;
        x8[k] = enc_fp8x4(v.x, v.y, v.z, v.w);
        continue;
      }
      const float4* sp; f16x4* dp;
      k -= n0;
      if (k < 147456) {
        int s = k / 49152, r = k % 49152, m = r / 16384, off = r % 16384;
        const float* w = (m == 0) ? Wq : (m == 1) ? Wk : Wv;
        int dblk = (m == 0) ? 0 : (m == 1) ? 32768 : 16384;
        sp = (const float4*)(w + s * 65536) + off;
        dp = (f16x4*)wqvk + s * 49152 + dblk + off;
      } else {
        k -= 147456;
        sp = (const float4*)Wd2 + k; dp = (f16x4*)wd2h + k;
      }
      float4 v = *sp;
      f16x4 o; o[0] = (f16)v.x; o[1] = (f16)v.y; o[2] = (f16)v.z; o[3] = (f16)v.w;
      *dp = o;
    }
  } else if (b < 2067) {
    // ---- enc table ----
    int id = (b - 2048) * 256 + threadIdx.x;
    if (id >= 3 * 1600) return;
    int s = id / 1600, c = id % 1600, db = c >> 4, ab = c & 15;
    const float* de = dist_emb + (size_t)(s * 100 + db) * 16;
    const float* ae = dir_emb + (size_t)(s * 16 + ab) * 16;
    const float* w1 = Wsp1 + s * 1024;
    const float* b1 = bsp1 + s * 32;
    const float* w2 = Wsp2 + s * 32;
    float enc = bsp2[s];
    for (int j = 0; j < 32; ++j) {
      float a = b1[j];
      const float* wr = w1 + j * 32;
#pragma unroll
      for (int i = 0; i < 16; ++i) a += de[i] * wr[i];
#pragma unroll
      for (int i = 0; i < 16; ++i) a += ae[i] * wr[16 + i];
      enc += fmaxf(a, 0.0f) * w2[j];
    }
    enc_tab[id] = enc;
  } else {
    // ---- histograms ----
    int e = (b - 2067) * 256 + threadIdx.x;
    if (e < E) {
      atomicAdd(&deg_i[eidx[e]], 1);
      atomicAdd(&indeg_i[eidx[E + e]], 1);
    }
    if (e < N) atomicAdd(&cellcnt[cell_of(coords, e)], 1);
  }
}

// ===================== Wfo = Wf_s @ Wo_s ; block y==3 computes fused bias =====================
__global__ __launch_bounds__(256) void wfo_kernel(
    const float* __restrict__ Wf, const float* __restrict__ Wo,
    const float* __restrict__ bo, const float* __restrict__ bf,
    f16* __restrict__ wfo, float* __restrict__ bias_f)
{
  const int j = threadIdx.x;
  if (blockIdx.y == 3) {
    if (blockIdx.x != 0) return;
    float acc = bf[j];
    const float* wr = Wf + (size_t)j * 768;
    for (int t = 0; t < 768; ++t) acc = fmaf(bo[t], wr[t], acc);
    bias_f[j] = acc;
    return;
  }
  __shared__ float wrow[256];
  const int o = blockIdx.x, s = blockIdx.y;
  wrow[j] = Wf[o * 768 + s * 256 + j];
  __syncthreads();
  const float* wo = Wo + (size_t)s * 65536 + j;
  float acc = 0.f;
#pragma unroll 8
  for (int m = 0; m < 256; ++m) acc = fmaf(wrow[m], wo[(size_t)m * 256], acc);
  wfo[(size_t)o * 768 + s * 256 + j] = (f16)acc;
}

// ===================== exclusive scans: one block per pass (dptr, sptr, cptr) =====================
__global__ __launch_bounds__(1024) void scan_kernel(const int* __restrict__ indeg,
                                                    const int* __restrict__ deg,
                                                    const int* __restrict__ cellcnt,
                                                    int* dptr, int* sptr, int* cptr, int N)
{
  __shared__ int lds[1024];
  const int tid = threadIdx.x;
  const int pass = blockIdx.x;
  const int* in = (pass == 0) ? indeg : (pass == 1) ? deg : cellcnt;
  int* out = (pass == 0) ? dptr : (pass == 1) ? sptr : cptr;
  int len = (pass == 2) ? 400 : N;
  int base = tid * 16;
  int loc[16];
  int sum = 0;
#pragma unroll
  for (int j = 0; j < 16; ++j) {
    int v = (base + j < len) ? in[base + j] : 0;
    loc[j] = sum; sum += v;
  }
  lds[tid] = sum;
  __syncthreads();
  for (int off = 1; off < 1024; off <<= 1) {
    int t = (tid >= off) ? lds[tid - off] : 0;
    __syncthreads();
    lds[tid] += t;
    __syncthreads();
  }
  int prev = tid ? lds[tid - 1] : 0;
#pragma unroll
  for (int j = 0; j < 16; ++j)
    if (base + j < len) out[base + j] = prev + loc[j];
  if (tid == 1023) out[len] = lds[1023];
}

// ===================== CSR scatter + per-edge geometry bins + cell scatter =====================
__global__ __launch_bounds__(256) void scatter_kernel(
    const int* __restrict__ eidx, const float* __restrict__ coords,
    const int* __restrict__ dptr, const int* __restrict__ sptr, const int* __restrict__ cptr,
    int* fill_d, int* fill_s, int* fill_c,
    int2* __restrict__ erec, int* __restrict__ sdst, float2* __restrict__ scoord, int E, int N)
{
  int e = blockIdx.x * 256 + threadIdx.x;
  if (e < E) {
    int s = eidx[e], d = eidx[E + e];
    float rx = coords[2 * s] - coords[2 * d];
    float ry = coords[2 * s + 1] - coords[2 * d + 1];
    float dist = sqrtf(rx * rx + ry * ry);
    float ang = atan2f(ry, rx);
    int ab = (int)((ang + 3.14159265358979323846f) / 6.28318530717958647692f * 15.0f);
    ab = ab < 0 ? 0 : (ab > 15 ? 15 : ab);
    int b0 = (int)((dist / 500.0f) * 99.0f);  b0 = b0 < 0 ? 0 : (b0 > 99 ? 99 : b0);
    int b1 = (int)((dist / 1000.0f) * 99.0f); b1 = b1 < 0 ? 0 : (b1 > 99 ? 99 : b1);
    int b2 = (int)((dist / 2000.0f) * 99.0f); b2 = b2 < 0 ? 0 : (b2 > 99 ? 99 : b2);
    unsigned pb = (unsigned)b0 | ((unsigned)b1 << 7) | ((unsigned)b2 << 14) | ((unsigned)ab << 21);
    int pd = dptr[d] + atomicAdd(&fill_d[d], 1);
    erec[pd] = make_int2(s, (int)pb);
    int ps = sptr[s] + atomicAdd(&fill_s[s], 1);
    sdst[ps] = d;
  }
  if (e < N) {
    int cid = cell_of(coords, e);
    int pc = cptr[cid] + atomicAdd(&fill_c[cid], 1);
    scoord[pc] = ((const float2*)coords)[e];
  }
}

// ===================== node stats: spatial density (cells) + fvar (slot-layout), wave/node =====================
__global__ __launch_bounds__(256) void node_stats_kernel(
    const float* __restrict__ coords, const float2* __restrict__ scoord,
    const int* __restrict__ cptr,
    const float* __restrict__ x, const unsigned* __restrict__ x8,
    const int* __restrict__ sptr, const int* __restrict__ sdst,
    int* __restrict__ sp_i, float* __restrict__ fvar, int N)
{
  int wv = threadIdx.x >> 6, lane = threadIdx.x & 63;
  int node = blockIdx.x * 4 + wv;
  if (node >= N) return;

  float cx = coords[2 * node], cy = coords[2 * node + 1];
  {
    int gx = (int)(cx * 0.02f); gx = gx < 0 ? 0 : (gx > 19 ? 19 : gx);
    int gy = (int)(cy * 0.02f); gy = gy < 0 ? 0 : (gy > 19 ? 19 : gy);
    int x0 = gx > 0 ? gx - 1 : 0, x1 = gx < 19 ? gx + 1 : 19;
    int y0 = gy > 0 ? gy - 1 : 0, y1 = gy < 19 ? gy + 1 : 19;
    int cnt = 0;
    for (int r = y0; r <= y1; ++r) {
      int j0 = cptr[r * 20 + x0], j1 = cptr[r * 20 + x1 + 1];
      for (int j = j0 + lane; j < j1; j += 64) {
        float2 c = scoord[j];
        float dx = cx - c.x, dy = cy - c.y;
        cnt += (dx * dx + dy * dy <= 2500.0f) ? 1 : 0;
      }
    }
    cnt += __shfl_xor(cnt, 1);  cnt += __shfl_xor(cnt, 2);  cnt += __shfl_xor(cnt, 4);
    cnt += __shfl_xor(cnt, 8);  cnt += __shfl_xor(cnt, 16); cnt += __shfl_xor(cnt, 32);
    if (lane == 0) sp_i[node] = cnt;
  }

  const int slot = lane >> 3, w = lane & 7;
  float sum[32];
#pragma unroll
  for (int i = 0; i < 32; ++i) sum[i] = 0.f;
  int e0 = sptr[node], e1 = sptr[node + 1];
  int nit = (e1 - e0 + 7) >> 3;
  for (int it = 0; it < nit; ++it) {
    int e = e0 + it * 8 + slot;
    bool valid = e < e1;
    int dd = sdst[valid ? e : e1 - 1];
    const unsigned* xp = x8 + dd * 64 + w * 8;
    uint4 a = *(const uint4*)xp;
    uint4 b = *(const uint4*)(xp + 4);
    float vm = valid ? 1.f : 0.f;
    unsigned wd[8] = {a.x, a.y, a.z, a.w, b.x, b.y, b.z, b.w};
#pragma unroll
    for (int k = 0; k < 8; ++k) {
      float4 f = dec_fp8x4(wd[k]);
      sum[k*4+0] = fmaf(vm, f.x, sum[k*4+0]);
      sum[k*4+1] = fmaf(vm, f.y, sum[k*4+1]);
      sum[k*4+2] = fmaf(vm, f.z, sum[k*4+2]);
      sum[k*4+3] = fmaf(vm, f.w, sum[k*4+3]);
    }
  }
#pragma unroll
  for (int i = 0; i < 32; ++i) {
    sum[i] += __shfl_xor(sum[i], 8);
    sum[i] += __shfl_xor(sum[i], 16);
    sum[i] += __shfl_xor(sum[i], 32);
  }
  float rcnt = 1.0f / fmaxf((float)(e1 - e0), 1.0f);
  const float4* xp4 = (const float4*)(x + (size_t)node * 256 + w * 32);
  float ss = 0.f;
#pragma unroll
  for (int k = 0; k < 8; ++k) {
    float4 xm = xp4[k];
    float d0 = xm.x - sum[k*4+0] * rcnt;
    float d1 = xm.y - sum[k*4+1] * rcnt;
    float d2 = xm.z - sum[k*4+2] * rcnt;
    float d3 = xm.w - sum[k*4+3] * rcnt;
    ss += d0*d0 + d1*d1 + d2*d2 + d3*d3;
  }
  ss += __shfl_xor(ss, 1);  ss += __shfl_xor(ss, 2);  ss += __shfl_xor(ss, 4);
  ss += __shfl_xor(ss, 8);  ss += __shfl_xor(ss, 16); ss += __shfl_xor(ss, 32);
  if (lane == 0) fvar[node] = sqrtf(ss * 0.125f);
}

// ===================== global maxes: single block, LDS tree =====================
__global__ __launch_bounds__(1024) void maxred_kernel(
    const int* __restrict__ sptr, const int* __restrict__ sp_i,
    const float* __restrict__ fvar, float* __restrict__ maxf, int N)
{
  __shared__ float l0[1024], l1[1024], l2[1024];
  int tid = threadIdx.x;
  float m0 = 0.f, m1 = 0.f, m2 = 0.f;
  for (int i = tid; i < N; i += 1024) {
    m0 = fmaxf(m0, (float)(sptr[i + 1] - sptr[i]));
    m1 = fmaxf(m1, (float)(sp_i[i] - 1));
    m2 = fmaxf(m2, fvar[i]);
  }
  l0[tid] = m0; l1[tid] = m1; l2[tid] = m2;
  __syncthreads();
  for (int off = 512; off > 0; off >>= 1) {
    if (tid < off) {
      l0[tid] = fmaxf(l0[tid], l0[tid + off]);
      l1[tid] = fmaxf(l1[tid], l1[tid + off]);
      l2[tid] = fmaxf(l2[tid], l2[tid + off]);
    }
    __syncthreads();
  }
  if (tid == 0) { maxf[0] = l0[0]; maxf[1] = l1[0]; maxf[2] = l2[0]; }
}

// ===================== per-scale hidden h = relu(dens @ Wd1^T + bd1), batched over scales =====================
__global__ __launch_bounds__(256) void h_kernel(
    const int* __restrict__ sptr, const int* __restrict__ sp_i, const float* __restrict__ fvar,
    const float* __restrict__ maxf, const float* __restrict__ Wd1,
    const float* __restrict__ bd1, f16* __restrict__ hbuf, int N, int Mp)
{
  int id = blockIdx.x * 256 + threadIdx.x;
  if (id >= N * 128) return;
  int s = blockIdx.y;
  int node = id >> 7, j = id & 127;
  float dm = maxf[0] + 1e-8f;
  float sm = maxf[1] + 1e-8f;
  float fm = maxf[2] + 1e-8f;
  float d0 = (float)(sptr[node + 1] - sptr[node]) / dm;
  float d1 = (float)(sp_i[node] - 1) / sm;
  float d2 = fvar[node] / fm;
  const float* wr = Wd1 + s * 384 + j * 3;
  float h = fmaxf(wr[0] * d0 + wr[1] * d1 + wr[2] * d2 + bd1[s * 128 + j], 0.0f);
  hbuf[(size_t)s * Mp * 128 + (size_t)node * 128 + j] = (f16)h;
}

// ===================== fp16 MFMA GEMM, scale-batched, XOR-swizzled LDS =====================
// outMode 0: f32 out; 1: f16 out; 2: qkv fused record (q->Cv f16; v,k->Cv2 1KB record).
__global__ __launch_bounds__(256) void gemm_bt_f16(
    const f16* __restrict__ A, int lda, long sA,
    const f16* __restrict__ B, int ldb, long sB,
    const float* __restrict__ bias, int sBias,
    void* __restrict__ Cv, int ldc, long sC, int K, int Mstore, int outMode,
    unsigned char* __restrict__ Cv2, long sC2)
{
  __shared__ f16 As[128 * 64];
  __shared__ f16 Bs[128 * 64];
  const int s = blockIdx.z;
  const int tid = threadIdx.x;
  const int lane = tid & 63;
  const int w = tid >> 6;
  const int wr = (w >> 1) * 64, wc = (w & 1) * 64;
  const int srow = tid >> 3;
  const int scol = (((tid & 7) ^ (srow & 7))) * 8;   // pre-swizzled source (rule #21)
  const f16* Ab = A + (size_t)s * sA + (size_t)(blockIdx.x * 128 + srow) * lda + scol;
  const f16* Bb = B + (size_t)s * sB + (size_t)(blockIdx.y * 128 + srow) * ldb + scol;
  char* Asl = (char*)As + tid * 16;
  char* Bsl = (char*)Bs + tid * 16;

  f32x4 acc[4][4] = {};

  for (int kt = 0; kt < K; kt += 64) {
    __syncthreads();
#pragma unroll
    for (int i = 0; i < 4; ++i) {
      gld_lds16(Ab + (size_t)i * 32 * lda + kt, Asl + i * 4096);
      gld_lds16(Bb + (size_t)i * 32 * ldb + kt, Bsl + i * 4096);
    }
    __syncthreads();
#pragma unroll
    for (int kq = 0; kq < 2; ++kq) {
      const int krd = kq * 32 + (lane >> 4) * 8;
      const int kc = krd >> 3;
      f16x8 af[4], bfr[4];
#pragma unroll
      for (int t = 0; t < 4; ++t) {
        const int ra = wr + t * 16 + (lane & 15);
        const int rb = wc + t * 16 + (lane & 15);
        af[t]  = *(const f16x8*)&As[ra * 64 + (kc ^ (ra & 7)) * 8];
        bfr[t] = *(const f16x8*)&Bs[rb * 64 + (kc ^ (rb & 7)) * 8];
      }
#pragma unroll
      for (int mi = 0; mi < 4; ++mi)
#pragma unroll
        for (int ni = 0; ni < 4; ++ni)
          acc[mi][ni] = __builtin_amdgcn_mfma_f32_16x16x32_f16(af[mi], bfr[ni], acc[mi][ni], 0, 0, 0);
    }
  }

  const int r0 = (lane >> 4) << 2;
  const int c0 = lane & 15;
#pragma unroll
  for (int mi = 0; mi < 4; ++mi) {
#pragma unroll
    for (int ni = 0; ni < 4; ++ni) {
      int col = blockIdx.y * 128 + wc + ni * 16 + c0;
      float bv = bias ? bias[s * sBias + col] : 0.0f;
#pragma unroll
      for (int r = 0; r < 4; ++r) {
        int row = blockIdx.x * 128 + wr + mi * 16 + r0 + r;
        if (row < Mstore) {
          float v = acc[mi][ni][r] + bv;
          if (outMode == 0) {
            ((float*)Cv)[(size_t)s * sC + (size_t)row * ldc + col] = v;
          } else if (outMode == 1) {
            ((f16*)Cv)[(size_t)s * sC + (size_t)row * ldc + col] = (f16)v;
          } else {
            if (col < 256) {
              ((f16*)Cv)[(size_t)s * sC + (size_t)row * 256 + col] = (f16)v;
            } else if (col < 512) {
              int vc = col - 256; int h = vc >> 5, j = vc & 31;
              *(f16*)(Cv2 + (size_t)s * sC2 + (size_t)row * 1024 + h * 128 + 64 + 2 * j) = (f16)v;
            } else {
              int kc2 = col - 512; int h = kc2 >> 5, j = kc2 & 31;
              unsigned pk = __builtin_amdgcn_cvt_pk_fp8_f32(v, v, 0u, false);
              Cv2[(size_t)s * sC2 + (size_t)row * 1024 + h * 128 + j] = (unsigned char)(pk & 0xffu);
            }
          }
        }
      }
    }
  }
}

// ===================== normalize df rows -> dfn (fp8) into fused record, batched over scales ==========
__global__ __launch_bounds__(256) void norm_kernel(const f16* __restrict__ dfh,
                                                   unsigned char* __restrict__ rec0, int N, int Mp)
{
  int wv = threadIdx.x >> 6, lane = threadIdx.x & 63;
  int node = blockIdx.x * 4 + wv;
  if (node >= N) return;
  int s = blockIdx.y;
  float4 d = ld4h(dfh + (size_t)s * Mp * 256 + (size_t)node * 256 + lane * 4);
  float ss = d.x * d.x + d.y * d.y + d.z * d.z + d.w * d.w;
  ss += __shfl_xor(ss, 1);  ss += __shfl_xor(ss, 2);  ss += __shfl_xor(ss, 4);
  ss += __shfl_xor(ss, 8);  ss += __shfl_xor(ss, 16); ss += __shfl_xor(ss, 32);
  float rn = 1.0f / fmaxf(sqrtf(ss), 1e-8f);
  unsigned* recw = (unsigned*)(rec0 + (size_t)s * Mp * 1024);
  recw[node * 256 + (lane >> 3) * 32 + 8 + (lane & 7)] = enc_fp8x4(d.x * rn, d.y * rn, d.z * rn, d.w * rn);
}

// ===================== edge attention: wave/node, slot(8)x head(8), fused 1KB record ======
// qrec: f16 256/node. rec (per scale, node 1024B): head h: [0,32)k fp8 | [32,64)dfn fp8 | [64,128)v f16
// aggc: concat layout, row stride 768, scale s cols [s*256, s*256+256)
__global__ __launch_bounds__(256) void edge_attn(
    const f16* __restrict__ qrec0, const unsigned* __restrict__ rec0,
    const int2* __restrict__ erec, const int* __restrict__ dptr,
    const float* __restrict__ enc_tab, const float* __restrict__ temp,
    f16* __restrict__ aggc, int N, int Mp)
{
  int wv = threadIdx.x >> 6, lane = threadIdx.x & 63;
  int node = blockIdx.x * 4 + wv;
  if (node >= N) return;
  const int s = blockIdx.y;
  const int sshift = 7 * s;
  const f16* qrec = qrec0 + (size_t)s * Mp * 256;
  const unsigned* recw = rec0 + (size_t)s * Mp * 256;   // u32 units, 256 words/node
  const float* enc_s = enc_tab + s * 1600;

  const int slot = lane >> 3;   // edge slot 0..7
  const int hd   = lane & 7;    // head

  f16x8 qv[4];
  {
    const f16* qp = qrec + (size_t)node * 256 + hd * 32;
#pragma unroll
    for (int i = 0; i < 4; ++i) qv[i] = *(const f16x8*)(qp + i * 8);
  }
  unsigned diw[8];
  {
    const unsigned* dp = recw + node * 256 + hd * 32 + 8;
    uint4 a = *(const uint4*)dp;
    uint4 b = *(const uint4*)(dp + 4);
    diw[0]=a.x; diw[1]=a.y; diw[2]=a.z; diw[3]=a.w;
    diw[4]=b.x; diw[5]=b.y; diw[6]=b.z; diw[7]=b.w;
  }
  const float inv_th = 0.17677669529663687f / temp[s * 8 + hd];

  float m = -1e30f, z = 0.f;
  float acc[32];
#pragma unroll
  for (int i = 0; i < 32; ++i) acc[i] = 0.f;

  int e0 = dptr[node], e1 = dptr[node + 1];
  int nit = (e1 - e0 + 7) >> 3;
  for (int it = 0; it < nit; ++it) {
    int e = e0 + it * 8 + slot;
    bool valid = e < e1;
    int2 rec = erec[valid ? e : e1 - 1];
    int src = rec.x;
    unsigned pb = (unsigned)rec.y;
    const uint4* pR = (const uint4*)(recw + (size_t)src * 256 + hd * 32);
    uint4 ka = pR[0];
    uint4 kb = pR[1];
    uint4 da = pR[2];
    uint4 db = pR[3];
    f16x8 vs0 = as_h8(pR[4]);
    f16x8 vs1 = as_h8(pR[5]);
    f16x8 vs2 = as_h8(pR[6]);
    f16x8 vs3 = as_h8(pR[7]);
    float enc = enc_s[((pb >> sshift) & 127u) * 16 + (pb >> 21)];

    unsigned kw[8] = {ka.x, ka.y, ka.z, ka.w, kb.x, kb.y, kb.z, kb.w};
    unsigned dw[8] = {da.x, da.y, da.z, da.w, db.x, db.y, db.z, db.w};
    float qk0 = 0.f, qk1 = 0.f, qk2 = 0.f, qk3 = 0.f;
    float ds0 = 0.f, ds1 = 0.f, ds2 = 0.f, ds3 = 0.f;
#pragma unroll
    for (int w = 0; w < 8; ++w) {
      float4 kf = dec_fp8x4(kw[w]);
      f16x8 qq = qv[w >> 1];
      const int b = (w & 1) * 4;
      qk0 = fmaf((float)qq[b+0], kf.x, qk0);
      qk1 = fmaf((float)qq[b+1], kf.y, qk1);
      qk2 = fmaf((float)qq[b+2], kf.z, qk2);
      qk3 = fmaf((float)qq[b+3], kf.w, qk3);
      float4 df = dec_fp8x4(dw[w]);
      float4 dd = dec_fp8x4(diw[w]);
      ds0 = fmaf(dd.x, df.x, ds0);
      ds1 = fmaf(dd.y, df.y, ds1);
      ds2 = fmaf(dd.z, df.z, ds2);
      ds3 = fmaf(dd.w, df.w, ds3);
    }
    float qk = (qk0 + qk1) + (qk2 + qk3);
    float ds = (ds0 + ds1) + (ds2 + ds3);
    ds += __shfl_xor(ds, 1); ds += __shfl_xor(ds, 2); ds += __shfl_xor(ds, 4);

    float sc = (qk * inv_th + enc) * (1.0f + 0.5f * ds);
    sc = valid ? sc : -1e30f;
    if (__any(sc > m + 8.0f)) {
      float mn = fmaxf(m, sc);
      float rs = __expf(m - mn);
      z *= rs;
#pragma unroll
      for (int i = 0; i < 32; ++i) acc[i] *= rs;
      m = mn;
    }
    float p = __expf(sc - m) * (valid ? 1.0f : 0.0f);
    z += p;
#pragma unroll
    for (int j = 0; j < 8; ++j) acc[j]      = fmaf(p, (float)vs0[j], acc[j]);
#pragma unroll
    for (int j = 0; j < 8; ++j) acc[8 + j]  = fmaf(p, (float)vs1[j], acc[8 + j]);
#pragma unroll
    for (int j = 0; j < 8; ++j) acc[16 + j] = fmaf(p, (float)vs2[j], acc[16 + j]);
#pragma unroll
    for (int j = 0; j < 8; ++j) acc[24 + j] = fmaf(p, (float)vs3[j], acc[24 + j]);
  }

  // merge the 8 slots (lanes differing in bits 3..5), same head
  float M = m;
  M = fmaxf(M, __shfl_xor(M, 8));
  M = fmaxf(M, __shfl_xor(M, 16));
  M = fmaxf(M, __shfl_xor(M, 32));
  float f = __expf(m - M);
  z *= f;
  z += __shfl_xor(z, 8); z += __shfl_xor(z, 16); z += __shfl_xor(z, 32);
#pragma unroll
  for (int i = 0; i < 32; ++i) {
    float a = acc[i] * f;
    a += __shfl_xor(a, 8); a += __shfl_xor(a, 16); a += __shfl_xor(a, 32);
    acc[i] = a;
  }
  float rz = 1.0f / (z + 1e-16f);
  if (slot == 0) {
    f16* op = aggc + (size_t)node * 768 + s * 256 + hd * 32;
#pragma unroll
    for (int w = 0; w < 4; ++w) {
      f16x8 o;
#pragma unroll
      for (int j = 0; j < 8; ++j) o[j] = (f16)(acc[w * 8 + j] * rz);
      *(f16x8*)(op + w * 8) = o;
    }
  }
}

// ===================== host launcher =====================
extern "C" void kernel_launch(void* const* d_in, const int* in_sizes, int n_in,
                              void* d_out, int out_size, void* d_ws, size_t ws_size,
                              hipStream_t stream)
{
  const float* x      = (const float*)d_in[0];
  const float* coords = (const float*)d_in[1];
  const int*   eidx   = (const int*)  d_in[2];
  const float* Wq   = (const float*)d_in[3];
  const float* Wk   = (const float*)d_in[4];
  const float* Wv   = (const float*)d_in[5];
  const float* Wo   = (const float*)d_in[6];
  const float* bo   = (const float*)d_in[7];
  const float* temp = (const float*)d_in[8];
  const float* dist_emb = (const float*)d_in[9];
  const float* dir_emb  = (const float*)d_in[10];
  const float* Wsp1 = (const float*)d_in[11];
  const float* bsp1 = (const float*)d_in[12];
  const float* Wsp2 = (const float*)d_in[13];
  const float* bsp2 = (const float*)d_in[14];
  const float* Wd1  = (const float*)d_in[15];
  const float* bd1  = (const float*)d_in[16];
  const float* Wd2  = (const float*)d_in[17];
  const float* bd2  = (const float*)d_in[18];
  const float* Wf   = (const float*)d_in[19];
  const float* bf   = (const float*)d_in[20];
  (void)n_in; (void)out_size; (void)ws_size;

  const int N  = in_sizes[0] / 256;
  const int E  = in_sizes[2] / 2;
  const int Mp = ((N + 127) / 128) * 128;

  char* p = (char*)d_ws;
  auto alloc = [&](size_t b) -> void* {
    void* r = (void*)p;
    p += (b + 255) & ~(size_t)255;
    return r;
  };

  f16*      x_h   = (f16*)     alloc((size_t)Mp * 256 * 2);
  unsigned* x8    = (unsigned*)alloc((size_t)Mp * 256);
  f16*      qrec3 = (f16*)     alloc((size_t)3 * Mp * 256 * 2);        // q per node per scale
  unsigned char* rec3 = (unsigned char*)alloc((size_t)3 * Mp * 1024);  // fused k|dfn|v records
  f16*      hbuf3 = (f16*)     alloc((size_t)3 * Mp * 128 * 2);
  f16*      dfh3  = (f16*)     alloc((size_t)3 * Mp * 256 * 2);
  f16*      aggc  = (f16*)     alloc((size_t)Mp * 768 * 2);            // concat agg, stride 768
  f16*      wqvk  = (f16*)     alloc((size_t)3 * 768 * 256 * 2);
  f16*      wfo   = (f16*)     alloc((size_t)256 * 768 * 2);
  float*    bias_f = (float*)  alloc(256 * 4);
  f16*      wd2h  = (f16*)     alloc((size_t)3 * 256 * 128 * 2);
  float*    enc_tab = (float*) alloc((size_t)3 * 1600 * 4);
  int*    dptr = (int*)   alloc((size_t)(N + 1) * 4);
  int*    sptr = (int*)   alloc((size_t)(N + 1) * 4);
  int*    cptr = (int*)   alloc((size_t)401 * 4);
  int2*   erec = (int2*)  alloc((size_t)E * 8);
  int*    sdst = (int*)   alloc((size_t)E * 4);
  float2* scoord = (float2*)alloc((size_t)N * 8);
  float*  fvar = (float*) alloc((size_t)N * 4);
  int*    sp_i = (int*)   alloc((size_t)N * 4);
  float*  maxf = (float*) alloc(4 * 4);
  // ---- zeroed-every-call block ----
  char* z0 = p;
  int* deg_i   = (int*)alloc((size_t)N * 4);
  int* indeg_i = (int*)alloc((size_t)N * 4);
  int* fill_d  = (int*)alloc((size_t)N * 4);
  int* fill_s  = (int*)alloc((size_t)N * 4);
  int* cellcnt = (int*)alloc(400 * 4);
  int* fill_c  = (int*)alloc(400 * 4);
  size_t zbytes = (size_t)(p - z0);
  hipMemsetAsync(z0, 0, zbytes, stream);

  // 1. prep: cast + enc tables + histograms (one dispatch)
  {
    int histBlocks = (E + 255) / 256;
    prep_kernel<<<2067 + histBlocks, 256, 0, stream>>>(
        x, Wq, Wk, Wv, Wd2, x_h, x8, wqvk, wd2h,
        dist_emb, dir_emb, Wsp1, bsp1, Wsp2, bsp2, enc_tab,
        eidx, coords, deg_i, indeg_i, cellcnt, E, N);
  }
  // 2. fused output-projection weights + bias (independent)
  wfo_kernel<<<dim3(256, 4), 256, 0, stream>>>(Wf, Wo, bo, bf, wfo, bias_f);
  // 3. scans (3 independent blocks)
  scan_kernel<<<3, 1024, 0, stream>>>(indeg_i, deg_i, cellcnt, dptr, sptr, cptr, N);
  // 4. CSR scatter + edge bins + cell scatter
  scatter_kernel<<<(E + 255) / 256, 256, 0, stream>>>(eidx, coords, dptr, sptr, cptr,
                                                      fill_d, fill_s, fill_c, erec, sdst, scoord, E, N);
  // 5. node stats: spatial density + fvar
  node_stats_kernel<<<(N + 3) / 4, 256, 0, stream>>>(coords, scoord, cptr, x, x8,
                                                     sptr, sdst, sp_i, fvar, N);
  // 6. maxes
  maxred_kernel<<<1, 1024, 0, stream>>>(sptr, sp_i, fvar, maxf, N);

  const int mtiles = Mp / 128;
  // 7. density hidden layer, all scales
  h_kernel<<<dim3((N * 128 + 255) / 256, 3), 256, 0, stream>>>(sptr, sp_i, fvar, maxf,
                                                               Wd1, bd1, hbuf3, N, Mp);
  // 8. df = h @ Wd2^T + bd2 (f16), all scales
  gemm_bt_f16<<<dim3(mtiles, 2, 3), 256, 0, stream>>>(hbuf3, 128, (long)Mp * 128,
                                                      wd2h, 128, 32768, bd2, 256,
                                                      dfh3, 256, (long)Mp * 256, 128, Mp, 1,
                                                      nullptr, 0);
  // 9. normalize -> fp8 dfn into fused record, all scales
  norm_kernel<<<dim3((N + 3) / 4, 3), 256, 0, stream>>>(dfh3, rec3, N, Mp);
  // 10. q (f16 -> qrec) and v,k (-> fused record) in one GEMM, all scales
  gemm_bt_f16<<<dim3(mtiles, 6, 3), 256, 0, stream>>>(x_h, 256, 0,
                                                      wqvk, 256, 196608, nullptr, 0,
                                                      qrec3, 256, (long)Mp * 256, 256, Mp, 2,
                                                      rec3, (long)Mp * 1024);
  // 11. edge attention + scatter softmax + aggregate, all scales (batched)
  edge_attn<<<dim3((N + 3) / 4, 3), 256, 0, stream>>>(qrec3, (const unsigned*)rec3, erec, dptr,
                                                      enc_tab, temp, aggc, N, Mp);
  // 12. fused (Wo then Wf) GEMM: out = aggc @ Wfo^T + bias_f  -> d_out f32
  gemm_bt_f16<<<dim3(mtiles, 2, 1), 256, 0, stream>>>(aggc, 768, 0,
                                                      wfo, 768, 0, bias_f, 0,
                                                      d_out, 256, 0, 768, N, 0,
                                                      nullptr, 0);
}

// Round 10
// 425.955 us; speedup vs baseline: 1.1166x; 1.1166x over previous
//
#include <hip/hip_runtime.h>

typedef _Float16 f16;
typedef _Float16 f16x4 __attribute__((ext_vector_type(4)));
typedef _Float16 f16x8 __attribute__((ext_vector_type(8)));
typedef float    f32x4 __attribute__((ext_vector_type(4)));
typedef float    fv2   __attribute__((ext_vector_type(2)));

__device__ __forceinline__ float4 ld4h(const f16* p) {
  f16x4 t = *(const f16x4*)p;
  return make_float4((float)t[0], (float)t[1], (float)t[2], (float)t[3]);
}

__device__ __forceinline__ float4 dec_fp8x4(unsigned u) {
  fv2 lo = __builtin_amdgcn_cvt_pk_f32_fp8(u, false);
  fv2 hi = __builtin_amdgcn_cvt_pk_f32_fp8(u, true);
  return make_float4(lo[0], lo[1], hi[0], hi[1]);
}

__device__ __forceinline__ unsigned enc_fp8x4(float a, float b, float c, float d) {
  unsigned v = 0;
  v = __builtin_amdgcn_cvt_pk_fp8_f32(a, b, v, false);
  v = __builtin_amdgcn_cvt_pk_fp8_f32(c, d, v, true);
  return v;
}

__device__ __forceinline__ void gld_lds16(const void* g, void* l) {
  __builtin_amdgcn_global_load_lds(
      (const __attribute__((address_space(1))) unsigned*)g,
      (__attribute__((address_space(3))) unsigned*)l, 16, 0, 0);
}

__device__ __forceinline__ int cell_of(const float* coords, int i) {
  int cx = (int)(coords[2 * i] * 0.02f);
  int cy = (int)(coords[2 * i + 1] * 0.02f);
  cx = cx < 0 ? 0 : (cx > 19 ? 19 : cx);
  cy = cy < 0 ? 0 : (cy > 19 ? 19 : cy);
  return cy * 20 + cx;
}

// ===================== prep: cast (blocks 0..2047) + enc tables (2048..2066) + hist (2067..) =====
// wqvk layout per scale: rows [0:256)=q, [256:512)=v, [512:768)=k
__global__ __launch_bounds__(256) void prep_kernel(
    const float* __restrict__ x, const float* __restrict__ Wq, const float* __restrict__ Wk,
    const float* __restrict__ Wv, const float* __restrict__ Wd2,
    f16* __restrict__ x_h, unsigned* __restrict__ x8, f16* __restrict__ wqvk,
    f16* __restrict__ wd2h,
    const float* __restrict__ dist_emb, const float* __restrict__ dir_emb,
    const float* __restrict__ Wsp1, const float* __restrict__ bsp1,
    const float* __restrict__ Wsp2, const float* __restrict__ bsp2,
    float* __restrict__ enc_tab,
    const int* __restrict__ eidx, const float* __restrict__ coords,
    int* deg_i, int* indeg_i, int* cellcnt, int E, int N)
{
  const int b = blockIdx.x;
  if (b < 2048) {
    const int n0 = N * 64;
    const int total = n0 + 147456 + 24576;
    for (int i = b * 256 + threadIdx.x; i < total; i += 2048 * 256) {
      int k = i;
      if (k < n0) {
        float4 v = ((const float4*)x)[k];
        f16x4 o; o[0] = (f16)v.x; o[1] = (f16)v.y; o[2] = (f16)v.z; o[3] = (f16)v.w;
        ((f16x4*)x_h)[k] = o;
        x8[k] = enc_fp8x4(v.x, v.y, v.z, v.w);
        continue;
      }
      const float4* sp; f16x4* dp;
      k -= n0;
      if (k < 147456) {
        int s = k / 49152, r = k % 49152, m = r / 16384, off = r % 16384;
        const float* w = (m == 0) ? Wq : (m == 1) ? Wk : Wv;
        int dblk = (m == 0) ? 0 : (m == 1) ? 32768 : 16384;
        sp = (const float4*)(w + s * 65536) + off;
        dp = (f16x4*)wqvk + s * 49152 + dblk + off;
      } else {
        k -= 147456;
        sp = (const float4*)Wd2 + k; dp = (f16x4*)wd2h + k;
      }
      float4 v = *sp;
      f16x4 o; o[0] = (f16)v.x; o[1] = (f16)v.y; o[2] = (f16)v.z; o[3] = (f16)v.w;
      *dp = o;
    }
  } else if (b < 2067) {
    int id = (b - 2048) * 256 + threadIdx.x;
    if (id >= 3 * 1600) return;
    int s = id / 1600, c = id % 1600, db = c >> 4, ab = c & 15;
    const float* de = dist_emb + (size_t)(s * 100 + db) * 16;
    const float* ae = dir_emb + (size_t)(s * 16 + ab) * 16;
    const float* w1 = Wsp1 + s * 1024;
    const float* b1 = bsp1 + s * 32;
    const float* w2 = Wsp2 + s * 32;
    float enc = bsp2[s];
    for (int j = 0; j < 32; ++j) {
      float a = b1[j];
      const float* wr = w1 + j * 32;
#pragma unroll
      for (int i = 0; i < 16; ++i) a += de[i] * wr[i];
#pragma unroll
      for (int i = 0; i < 16; ++i) a += ae[i] * wr[16 + i];
      enc += fmaxf(a, 0.0f) * w2[j];
    }
    enc_tab[id] = enc;
  } else {
    int e = (b - 2067) * 256 + threadIdx.x;
    if (e < E) {
      atomicAdd(&deg_i[eidx[e]], 1);
      atomicAdd(&indeg_i[eidx[E + e]], 1);
    }
    if (e < N) atomicAdd(&cellcnt[cell_of(coords, e)], 1);
  }
}

// ===================== Wfo = Wf_s @ Wo_s ; block y==3 computes fused bias =====================
__global__ __launch_bounds__(256) void wfo_kernel(
    const float* __restrict__ Wf, const float* __restrict__ Wo,
    const float* __restrict__ bo, const float* __restrict__ bf,
    f16* __restrict__ wfo, float* __restrict__ bias_f)
{
  const int j = threadIdx.x;
  if (blockIdx.y == 3) {
    if (blockIdx.x != 0) return;
    float acc = bf[j];
    const float* wr = Wf + (size_t)j * 768;
    for (int t = 0; t < 768; ++t) acc = fmaf(bo[t], wr[t], acc);
    bias_f[j] = acc;
    return;
  }
  __shared__ float wrow[256];
  const int o = blockIdx.x, s = blockIdx.y;
  wrow[j] = Wf[o * 768 + s * 256 + j];
  __syncthreads();
  const float* wo = Wo + (size_t)s * 65536 + j;
  float acc = 0.f;
#pragma unroll 8
  for (int m = 0; m < 256; ++m) acc = fmaf(wrow[m], wo[(size_t)m * 256], acc);
  wfo[(size_t)o * 768 + s * 256 + j] = (f16)acc;
}

// ===================== exclusive scans: one block per pass (dptr, sptr, cptr) =====================
__global__ __launch_bounds__(1024) void scan_kernel(const int* __restrict__ indeg,
                                                    const int* __restrict__ deg,
                                                    const int* __restrict__ cellcnt,
                                                    int* dptr, int* sptr, int* cptr, int N)
{
  __shared__ int lds[1024];
  const int tid = threadIdx.x;
  const int pass = blockIdx.x;
  const int* in = (pass == 0) ? indeg : (pass == 1) ? deg : cellcnt;
  int* out = (pass == 0) ? dptr : (pass == 1) ? sptr : cptr;
  int len = (pass == 2) ? 400 : N;
  int base = tid * 16;
  int loc[16];
  int sum = 0;
#pragma unroll
  for (int j = 0; j < 16; ++j) {
    int v = (base + j < len) ? in[base + j] : 0;
    loc[j] = sum; sum += v;
  }
  lds[tid] = sum;
  __syncthreads();
  for (int off = 1; off < 1024; off <<= 1) {
    int t = (tid >= off) ? lds[tid - off] : 0;
    __syncthreads();
    lds[tid] += t;
    __syncthreads();
  }
  int prev = tid ? lds[tid - 1] : 0;
#pragma unroll
  for (int j = 0; j < 16; ++j)
    if (base + j < len) out[base + j] = prev + loc[j];
  if (tid == 1023) out[len] = lds[1023];
}

// ===================== degree-descending counting-sort permutation (single block) =====================
__global__ __launch_bounds__(1024) void perm_kernel(const int* __restrict__ dptr,
                                                    int* __restrict__ perm, int N)
{
  __shared__ int cnt[256], scn[256], fill[256];
  const int tid = threadIdx.x;
  if (tid < 256) { cnt[tid] = 0; fill[tid] = 0; }
  __syncthreads();
  for (int n = tid; n < N; n += 1024) {
    int d = dptr[n + 1] - dptr[n];
    int key = 255 - (d > 255 ? 255 : d);   // descending degree
    atomicAdd(&cnt[key], 1);
  }
  __syncthreads();
  if (tid < 256) scn[tid] = cnt[tid];
  __syncthreads();
  for (int off = 1; off < 256; off <<= 1) {
    int v = 0;
    if (tid < 256 && tid >= off) v = scn[tid - off];
    __syncthreads();
    if (tid < 256) scn[tid] += v;
    __syncthreads();
  }
  for (int n = tid; n < N; n += 1024) {
    int d = dptr[n + 1] - dptr[n];
    int key = 255 - (d > 255 ? 255 : d);
    int pos = scn[key] - cnt[key] + atomicAdd(&fill[key], 1);
    perm[pos] = n;
  }
}

// ===================== CSR scatter + per-edge geometry bins + cell scatter =====================
__global__ __launch_bounds__(256) void scatter_kernel(
    const int* __restrict__ eidx, const float* __restrict__ coords,
    const int* __restrict__ dptr, const int* __restrict__ sptr, const int* __restrict__ cptr,
    int* fill_d, int* fill_s, int* fill_c,
    int2* __restrict__ erec, int* __restrict__ sdst, float2* __restrict__ scoord, int E, int N)
{
  int e = blockIdx.x * 256 + threadIdx.x;
  if (e < E) {
    int s = eidx[e], d = eidx[E + e];
    float rx = coords[2 * s] - coords[2 * d];
    float ry = coords[2 * s + 1] - coords[2 * d + 1];
    float dist = sqrtf(rx * rx + ry * ry);
    float ang = atan2f(ry, rx);
    int ab = (int)((ang + 3.14159265358979323846f) / 6.28318530717958647692f * 15.0f);
    ab = ab < 0 ? 0 : (ab > 15 ? 15 : ab);
    int b0 = (int)((dist / 500.0f) * 99.0f);  b0 = b0 < 0 ? 0 : (b0 > 99 ? 99 : b0);
    int b1 = (int)((dist / 1000.0f) * 99.0f); b1 = b1 < 0 ? 0 : (b1 > 99 ? 99 : b1);
    int b2 = (int)((dist / 2000.0f) * 99.0f); b2 = b2 < 0 ? 0 : (b2 > 99 ? 99 : b2);
    unsigned pb = (unsigned)b0 | ((unsigned)b1 << 7) | ((unsigned)b2 << 14) | ((unsigned)ab << 21);
    int pd = dptr[d] + atomicAdd(&fill_d[d], 1);
    erec[pd] = make_int2(s, (int)pb);
    int ps = sptr[s] + atomicAdd(&fill_s[s], 1);
    sdst[ps] = d;
  }
  if (e < N) {
    int cid = cell_of(coords, e);
    int pc = cptr[cid] + atomicAdd(&fill_c[cid], 1);
    scoord[pc] = ((const float2*)coords)[e];
  }
}

// ===================== node stats: spatial density (cells) + fvar (slot-layout), wave/node =====================
__global__ __launch_bounds__(256) void node_stats_kernel(
    const float* __restrict__ coords, const float2* __restrict__ scoord,
    const int* __restrict__ cptr,
    const float* __restrict__ x, const unsigned* __restrict__ x8,
    const int* __restrict__ sptr, const int* __restrict__ sdst,
    int* __restrict__ sp_i, float* __restrict__ fvar, int N)
{
  int wv = threadIdx.x >> 6, lane = threadIdx.x & 63;
  int node = blockIdx.x * 4 + wv;
  if (node >= N) return;

  float cx = coords[2 * node], cy = coords[2 * node + 1];
  {
    int gx = (int)(cx * 0.02f); gx = gx < 0 ? 0 : (gx > 19 ? 19 : gx);
    int gy = (int)(cy * 0.02f); gy = gy < 0 ? 0 : (gy > 19 ? 19 : gy);
    int x0 = gx > 0 ? gx - 1 : 0, x1 = gx < 19 ? gx + 1 : 19;
    int y0 = gy > 0 ? gy - 1 : 0, y1 = gy < 19 ? gy + 1 : 19;
    int cnt = 0;
    for (int r = y0; r <= y1; ++r) {
      int j0 = cptr[r * 20 + x0], j1 = cptr[r * 20 + x1 + 1];
      for (int j = j0 + lane; j < j1; j += 64) {
        float2 c = scoord[j];
        float dx = cx - c.x, dy = cy - c.y;
        cnt += (dx * dx + dy * dy <= 2500.0f) ? 1 : 0;
      }
    }
    cnt += __shfl_xor(cnt, 1);  cnt += __shfl_xor(cnt, 2);  cnt += __shfl_xor(cnt, 4);
    cnt += __shfl_xor(cnt, 8);  cnt += __shfl_xor(cnt, 16); cnt += __shfl_xor(cnt, 32);
    if (lane == 0) sp_i[node] = cnt;
  }

  const int slot = lane >> 3, w = lane & 7;
  float sum[32];
#pragma unroll
  for (int i = 0; i < 32; ++i) sum[i] = 0.f;
  int e0 = sptr[node], e1 = sptr[node + 1];
  int nit = (e1 - e0 + 7) >> 3;
  for (int it = 0; it < nit; ++it) {
    int e = e0 + it * 8 + slot;
    bool valid = e < e1;
    int dd = sdst[valid ? e : e1 - 1];
    const unsigned* xp = x8 + dd * 64 + w * 8;
    uint4 a = *(const uint4*)xp;
    uint4 b = *(const uint4*)(xp + 4);
    float vm = valid ? 1.f : 0.f;
    unsigned wd[8] = {a.x, a.y, a.z, a.w, b.x, b.y, b.z, b.w};
#pragma unroll
    for (int k = 0; k < 8; ++k) {
      float4 f = dec_fp8x4(wd[k]);
      sum[k*4+0] = fmaf(vm, f.x, sum[k*4+0]);
      sum[k*4+1] = fmaf(vm, f.y, sum[k*4+1]);
      sum[k*4+2] = fmaf(vm, f.z, sum[k*4+2]);
      sum[k*4+3] = fmaf(vm, f.w, sum[k*4+3]);
    }
  }
#pragma unroll
  for (int i = 0; i < 32; ++i) {
    sum[i] += __shfl_xor(sum[i], 8);
    sum[i] += __shfl_xor(sum[i], 16);
    sum[i] += __shfl_xor(sum[i], 32);
  }
  float rcnt = 1.0f / fmaxf((float)(e1 - e0), 1.0f);
  const float4* xp4 = (const float4*)(x + (size_t)node * 256 + w * 32);
  float ss = 0.f;
#pragma unroll
  for (int k = 0; k < 8; ++k) {
    float4 xm = xp4[k];
    float d0 = xm.x - sum[k*4+0] * rcnt;
    float d1 = xm.y - sum[k*4+1] * rcnt;
    float d2 = xm.z - sum[k*4+2] * rcnt;
    float d3 = xm.w - sum[k*4+3] * rcnt;
    ss += d0*d0 + d1*d1 + d2*d2 + d3*d3;
  }
  ss += __shfl_xor(ss, 1);  ss += __shfl_xor(ss, 2);  ss += __shfl_xor(ss, 4);
  ss += __shfl_xor(ss, 8);  ss += __shfl_xor(ss, 16); ss += __shfl_xor(ss, 32);
  if (lane == 0) fvar[node] = sqrtf(ss * 0.125f);
}

// ===================== global maxes: single block, LDS tree =====================
__global__ __launch_bounds__(1024) void maxred_kernel(
    const int* __restrict__ sptr, const int* __restrict__ sp_i,
    const float* __restrict__ fvar, float* __restrict__ maxf, int N)
{
  __shared__ float l0[1024], l1[1024], l2[1024];
  int tid = threadIdx.x;
  float m0 = 0.f, m1 = 0.f, m2 = 0.f;
  for (int i = tid; i < N; i += 1024) {
    m0 = fmaxf(m0, (float)(sptr[i + 1] - sptr[i]));
    m1 = fmaxf(m1, (float)(sp_i[i] - 1));
    m2 = fmaxf(m2, fvar[i]);
  }
  l0[tid] = m0; l1[tid] = m1; l2[tid] = m2;
  __syncthreads();
  for (int off = 512; off > 0; off >>= 1) {
    if (tid < off) {
      l0[tid] = fmaxf(l0[tid], l0[tid + off]);
      l1[tid] = fmaxf(l1[tid], l1[tid + off]);
      l2[tid] = fmaxf(l2[tid], l2[tid + off]);
    }
    __syncthreads();
  }
  if (tid == 0) { maxf[0] = l0[0]; maxf[1] = l1[0]; maxf[2] = l2[0]; }
}

// ===================== per-scale hidden h = relu(dens @ Wd1^T + bd1), batched over scales =====================
__global__ __launch_bounds__(256) void h_kernel(
    const int* __restrict__ sptr, const int* __restrict__ sp_i, const float* __restrict__ fvar,
    const float* __restrict__ maxf, const float* __restrict__ Wd1,
    const float* __restrict__ bd1, f16* __restrict__ hbuf, int N, int Mp)
{
  int id = blockIdx.x * 256 + threadIdx.x;
  if (id >= N * 128) return;
  int s = blockIdx.y;
  int node = id >> 7, j = id & 127;
  float dm = maxf[0] + 1e-8f;
  float sm = maxf[1] + 1e-8f;
  float fm = maxf[2] + 1e-8f;
  float d0 = (float)(sptr[node + 1] - sptr[node]) / dm;
  float d1 = (float)(sp_i[node] - 1) / sm;
  float d2 = fvar[node] / fm;
  const float* wr = Wd1 + s * 384 + j * 3;
  float h = fmaxf(wr[0] * d0 + wr[1] * d1 + wr[2] * d2 + bd1[s * 128 + j], 0.0f);
  hbuf[(size_t)s * Mp * 128 + (size_t)node * 128 + j] = (f16)h;
}

// ===================== fp16 MFMA GEMM, scale-batched, XOR-swizzled LDS, split fp8 output =====
__global__ __launch_bounds__(256) void gemm_bt_f16(
    const f16* __restrict__ A, int lda, long sA,
    const f16* __restrict__ B, int ldb, long sB,
    const float* __restrict__ bias, int sBias,
    void* __restrict__ Cv, int ldc, long sC, int K, int Mstore, int outMode,
    unsigned char* __restrict__ Cv2, int ldc2, long sC2, int ysplit)
{
  __shared__ f16 As[128 * 64];
  __shared__ f16 Bs[128 * 64];
  const int s = blockIdx.z;
  const int tid = threadIdx.x;
  const int lane = tid & 63;
  const int w = tid >> 6;
  const int wr = (w >> 1) * 64, wc = (w & 1) * 64;
  const int srow = tid >> 3;
  const int scol = (((tid & 7) ^ (srow & 7))) * 8;   // pre-swizzled source (rule #21)
  const f16* Ab = A + (size_t)s * sA + (size_t)(blockIdx.x * 128 + srow) * lda + scol;
  const f16* Bb = B + (size_t)s * sB + (size_t)(blockIdx.y * 128 + srow) * ldb + scol;
  char* Asl = (char*)As + tid * 16;
  char* Bsl = (char*)Bs + tid * 16;

  f32x4 acc[4][4] = {};

  for (int kt = 0; kt < K; kt += 64) {
    __syncthreads();
#pragma unroll
    for (int i = 0; i < 4; ++i) {
      gld_lds16(Ab + (size_t)i * 32 * lda + kt, Asl + i * 4096);
      gld_lds16(Bb + (size_t)i * 32 * ldb + kt, Bsl + i * 4096);
    }
    __syncthreads();
#pragma unroll
    for (int kq = 0; kq < 2; ++kq) {
      const int krd = kq * 32 + (lane >> 4) * 8;
      const int kc = krd >> 3;
      f16x8 af[4], bfr[4];
#pragma unroll
      for (int t = 0; t < 4; ++t) {
        const int ra = wr + t * 16 + (lane & 15);
        const int rb = wc + t * 16 + (lane & 15);
        af[t]  = *(const f16x8*)&As[ra * 64 + (kc ^ (ra & 7)) * 8];
        bfr[t] = *(const f16x8*)&Bs[rb * 64 + (kc ^ (rb & 7)) * 8];
      }
#pragma unroll
      for (int mi = 0; mi < 4; ++mi)
#pragma unroll
        for (int ni = 0; ni < 4; ++ni)
          acc[mi][ni] = __builtin_amdgcn_mfma_f32_16x16x32_f16(af[mi], bfr[ni], acc[mi][ni], 0, 0, 0);
    }
  }

  const int r0 = (lane >> 4) << 2;
  const int c0 = lane & 15;
  const bool f8p = ((int)blockIdx.y >= ysplit);
  const int cbase = f8p ? ((int)blockIdx.y - ysplit) * 128 : (int)blockIdx.y * 128;
#pragma unroll
  for (int mi = 0; mi < 4; ++mi) {
#pragma unroll
    for (int ni = 0; ni < 4; ++ni) {
      int col = cbase + wc + ni * 16 + c0;
      float bv = (!f8p && bias) ? bias[s * sBias + col] : 0.0f;
#pragma unroll
      for (int r = 0; r < 4; ++r) {
        int row = blockIdx.x * 128 + wr + mi * 16 + r0 + r;
        if (row < Mstore) {
          float v = acc[mi][ni][r] + bv;
          if (f8p) {
            unsigned pk = __builtin_amdgcn_cvt_pk_fp8_f32(v, v, 0u, false);
            Cv2[(size_t)s * sC2 + (size_t)row * ldc2 + col] = (unsigned char)(pk & 0xffu);
          } else if (outMode == 1) {
            ((f16*)Cv)[(size_t)s * sC + (size_t)row * ldc + col] = (f16)v;
          } else {
            ((float*)Cv)[(size_t)s * sC + (size_t)row * ldc + col] = v;
          }
        }
      }
    }
  }
}

// ===================== normalize df rows -> dfn (fp8), batched over scales =====================
__global__ __launch_bounds__(256) void norm_kernel(const f16* __restrict__ dfh,
                                                   unsigned* __restrict__ drec8, int N, int Mp)
{
  int wv = threadIdx.x >> 6, lane = threadIdx.x & 63;
  int node = blockIdx.x * 4 + wv;
  if (node >= N) return;
  int s = blockIdx.y;
  float4 d = ld4h(dfh + (size_t)s * Mp * 256 + (size_t)node * 256 + lane * 4);
  float ss = d.x * d.x + d.y * d.y + d.z * d.z + d.w * d.w;
  ss += __shfl_xor(ss, 1);  ss += __shfl_xor(ss, 2);  ss += __shfl_xor(ss, 4);
  ss += __shfl_xor(ss, 8);  ss += __shfl_xor(ss, 16); ss += __shfl_xor(ss, 32);
  float rn = 1.0f / fmaxf(sqrtf(ss), 1e-8f);
  drec8[(size_t)s * Mp * 64 + node * 64 + lane] = enc_fp8x4(d.x * rn, d.y * rn, d.z * rn, d.w * rn);
}

// ===================== edge attention: wave/node (perm-scheduled), slot(8)x head(8), batched scales =====
// nrec row (per node, f16, 512): [0:256)=q [256:512)=v ; krec8/drec8: fp8 (64 u32 words per node)
// aggc: concat layout, row stride 768, scale s cols [s*256, s*256+256)
__global__ __launch_bounds__(256) void edge_attn(
    const f16* __restrict__ nrec0, const unsigned* __restrict__ krec0,
    const unsigned* __restrict__ drec0, const int2* __restrict__ erec,
    const int* __restrict__ dptr, const int* __restrict__ perm,
    const float* __restrict__ enc_tab, const float* __restrict__ temp,
    f16* __restrict__ aggc, int N, int Mp)
{
  int wv = threadIdx.x >> 6, lane = threadIdx.x & 63;
  int node = blockIdx.x * 4 + wv;
  if (node >= N) return;
  node = perm[node];   // degree-descending schedule
  const int s = blockIdx.y;
  const int sshift = 7 * s;
  const f16* nrec = nrec0 + (size_t)s * Mp * 512;
  const unsigned* krec8 = krec0 + (size_t)s * Mp * 64;
  const unsigned* drec8 = drec0 + (size_t)s * Mp * 64;
  const float* enc_s = enc_tab + s * 1600;

  const int slot = lane >> 3;   // edge slot 0..7
  const int hd   = lane & 7;    // head

  f16x8 qv[4];
  {
    const f16* qp = nrec + (size_t)node * 512 + hd * 32;
#pragma unroll
    for (int i = 0; i < 4; ++i) qv[i] = *(const f16x8*)(qp + i * 8);
  }
  unsigned diw[8];
  {
    const unsigned* dp = drec8 + node * 64 + hd * 8;
    uint4 a = *(const uint4*)dp;
    uint4 b = *(const uint4*)(dp + 4);
    diw[0]=a.x; diw[1]=a.y; diw[2]=a.z; diw[3]=a.w;
    diw[4]=b.x; diw[5]=b.y; diw[6]=b.z; diw[7]=b.w;
  }
  const float inv_th = 0.17677669529663687f / temp[s * 8 + hd];

  float m = -1e30f, z = 0.f;
  float acc[32];
#pragma unroll
  for (int i = 0; i < 32; ++i) acc[i] = 0.f;

  int e0 = dptr[node], e1 = dptr[node + 1];
  int nit = (e1 - e0 + 7) >> 3;
  for (int it = 0; it < nit; ++it) {
    int e = e0 + it * 8 + slot;
    bool valid = e < e1;
    int2 rec = erec[valid ? e : e1 - 1];
    int src = rec.x;
    unsigned pb = (unsigned)rec.y;
    const unsigned* kp = krec8 + src * 64 + hd * 8;
    const unsigned* dp = drec8 + src * 64 + hd * 8;
    const f16* vp = nrec + (size_t)src * 512 + 256 + hd * 32;
    uint4 ka = *(const uint4*)kp;
    uint4 kb = *(const uint4*)(kp + 4);
    uint4 da = *(const uint4*)dp;
    uint4 db = *(const uint4*)(dp + 4);
    f16x8 vs0 = *(const f16x8*)vp;
    f16x8 vs1 = *(const f16x8*)(vp + 8);
    f16x8 vs2 = *(const f16x8*)(vp + 16);
    f16x8 vs3 = *(const f16x8*)(vp + 24);
    float enc = enc_s[((pb >> sshift) & 127u) * 16 + (pb >> 21)];

    unsigned kw[8] = {ka.x, ka.y, ka.z, ka.w, kb.x, kb.y, kb.z, kb.w};
    unsigned dw[8] = {da.x, da.y, da.z, da.w, db.x, db.y, db.z, db.w};
    float qk0 = 0.f, qk1 = 0.f, qk2 = 0.f, qk3 = 0.f;
    float ds0 = 0.f, ds1 = 0.f, ds2 = 0.f, ds3 = 0.f;
#pragma unroll
    for (int w = 0; w < 8; ++w) {
      float4 kf = dec_fp8x4(kw[w]);
      f16x8 qq = qv[w >> 1];
      const int b = (w & 1) * 4;
      qk0 = fmaf((float)qq[b+0], kf.x, qk0);
      qk1 = fmaf((float)qq[b+1], kf.y, qk1);
      qk2 = fmaf((float)qq[b+2], kf.z, qk2);
      qk3 = fmaf((float)qq[b+3], kf.w, qk3);
      float4 df = dec_fp8x4(dw[w]);
      float4 dd = dec_fp8x4(diw[w]);
      ds0 = fmaf(dd.x, df.x, ds0);
      ds1 = fmaf(dd.y, df.y, ds1);
      ds2 = fmaf(dd.z, df.z, ds2);
      ds3 = fmaf(dd.w, df.w, ds3);
    }
    float qk = (qk0 + qk1) + (qk2 + qk3);
    float ds = (ds0 + ds1) + (ds2 + ds3);
    ds += __shfl_xor(ds, 1); ds += __shfl_xor(ds, 2); ds += __shfl_xor(ds, 4);

    float sc = (qk * inv_th + enc) * (1.0f + 0.5f * ds);
    sc = valid ? sc : -1e30f;
    if (__any(sc > m + 8.0f)) {
      float mn = fmaxf(m, sc);
      float rs = __expf(m - mn);
      z *= rs;
#pragma unroll
      for (int i = 0; i < 32; ++i) acc[i] *= rs;
      m = mn;
    }
    float p = __expf(sc - m) * (valid ? 1.0f : 0.0f);
    z += p;
#pragma unroll
    for (int j = 0; j < 8; ++j) acc[j]      = fmaf(p, (float)vs0[j], acc[j]);
#pragma unroll
    for (int j = 0; j < 8; ++j) acc[8 + j]  = fmaf(p, (float)vs1[j], acc[8 + j]);
#pragma unroll
    for (int j = 0; j < 8; ++j) acc[16 + j] = fmaf(p, (float)vs2[j], acc[16 + j]);
#pragma unroll
    for (int j = 0; j < 8; ++j) acc[24 + j] = fmaf(p, (float)vs3[j], acc[24 + j]);
  }

  // merge the 8 slots (lanes differing in bits 3..5), same head
  float M = m;
  M = fmaxf(M, __shfl_xor(M, 8));
  M = fmaxf(M, __shfl_xor(M, 16));
  M = fmaxf(M, __shfl_xor(M, 32));
  float f = __expf(m - M);
  z *= f;
  z += __shfl_xor(z, 8); z += __shfl_xor(z, 16); z += __shfl_xor(z, 32);
#pragma unroll
  for (int i = 0; i < 32; ++i) {
    float a = acc[i] * f;
    a += __shfl_xor(a, 8); a += __shfl_xor(a, 16); a += __shfl_xor(a, 32);
    acc[i] = a;
  }
  float rz = 1.0f / (z + 1e-16f);
  if (slot == 0) {
    f16* op = aggc + (size_t)node * 768 + s * 256 + hd * 32;
#pragma unroll
    for (int w = 0; w < 4; ++w) {
      f16x8 o;
#pragma unroll
      for (int j = 0; j < 8; ++j) o[j] = (f16)(acc[w * 8 + j] * rz);
      *(f16x8*)(op + w * 8) = o;
    }
  }
}

// ===================== host launcher =====================
extern "C" void kernel_launch(void* const* d_in, const int* in_sizes, int n_in,
                              void* d_out, int out_size, void* d_ws, size_t ws_size,
                              hipStream_t stream)
{
  const float* x      = (const float*)d_in[0];
  const float* coords = (const float*)d_in[1];
  const int*   eidx   = (const int*)  d_in[2];
  const float* Wq   = (const float*)d_in[3];
  const float* Wk   = (const float*)d_in[4];
  const float* Wv   = (const float*)d_in[5];
  const float* Wo   = (const float*)d_in[6];
  const float* bo   = (const float*)d_in[7];
  const float* temp = (const float*)d_in[8];
  const float* dist_emb = (const float*)d_in[9];
  const float* dir_emb  = (const float*)d_in[10];
  const float* Wsp1 = (const float*)d_in[11];
  const float* bsp1 = (const float*)d_in[12];
  const float* Wsp2 = (const float*)d_in[13];
  const float* bsp2 = (const float*)d_in[14];
  const float* Wd1  = (const float*)d_in[15];
  const float* bd1  = (const float*)d_in[16];
  const float* Wd2  = (const float*)d_in[17];
  const float* bd2  = (const float*)d_in[18];
  const float* Wf   = (const float*)d_in[19];
  const float* bf   = (const float*)d_in[20];
  (void)n_in; (void)out_size; (void)ws_size;

  const int N  = in_sizes[0] / 256;
  const int E  = in_sizes[2] / 2;
  const int Mp = ((N + 127) / 128) * 128;

  char* p = (char*)d_ws;
  auto alloc = [&](size_t b) -> void* {
    void* r = (void*)p;
    p += (b + 255) & ~(size_t)255;
    return r;
  };

  f16*      x_h   = (f16*)     alloc((size_t)Mp * 256 * 2);
  unsigned* x8    = (unsigned*)alloc((size_t)Mp * 256);
  f16*      nrec3 = (f16*)     alloc((size_t)3 * Mp * 512 * 2);  // q|v per node per scale
  unsigned* krec3 = (unsigned*)alloc((size_t)3 * Mp * 256);
  unsigned* drec3 = (unsigned*)alloc((size_t)3 * Mp * 256);
  f16*      hbuf3 = (f16*)     alloc((size_t)3 * Mp * 128 * 2);
  f16*      dfh3  = (f16*)     alloc((size_t)3 * Mp * 256 * 2);
  f16*      aggc  = (f16*)     alloc((size_t)Mp * 768 * 2);      // concat agg, row stride 768
  f16*      wqvk  = (f16*)     alloc((size_t)3 * 768 * 256 * 2);
  f16*      wfo   = (f16*)     alloc((size_t)256 * 768 * 2);
  float*    bias_f = (float*)  alloc(256 * 4);
  f16*      wd2h  = (f16*)     alloc((size_t)3 * 256 * 128 * 2);
  float*    enc_tab = (float*) alloc((size_t)3 * 1600 * 4);
  int*    dptr = (int*)   alloc((size_t)(N + 1) * 4);
  int*    sptr = (int*)   alloc((size_t)(N + 1) * 4);
  int*    cptr = (int*)   alloc((size_t)401 * 4);
  int*    perm = (int*)   alloc((size_t)N * 4);
  int2*   erec = (int2*)  alloc((size_t)E * 8);
  int*    sdst = (int*)   alloc((size_t)E * 4);
  float2* scoord = (float2*)alloc((size_t)N * 8);
  float*  fvar = (float*) alloc((size_t)N * 4);
  int*    sp_i = (int*)   alloc((size_t)N * 4);
  float*  maxf = (float*) alloc(4 * 4);
  // ---- zeroed-every-call block ----
  char* z0 = p;
  int* deg_i   = (int*)alloc((size_t)N * 4);
  int* indeg_i = (int*)alloc((size_t)N * 4);
  int* fill_d  = (int*)alloc((size_t)N * 4);
  int* fill_s  = (int*)alloc((size_t)N * 4);
  int* cellcnt = (int*)alloc(400 * 4);
  int* fill_c  = (int*)alloc(400 * 4);
  size_t zbytes = (size_t)(p - z0);
  hipMemsetAsync(z0, 0, zbytes, stream);

  // 1. prep: cast + enc tables + histograms (one dispatch)
  {
    int histBlocks = (E + 255) / 256;
    prep_kernel<<<2067 + histBlocks, 256, 0, stream>>>(
        x, Wq, Wk, Wv, Wd2, x_h, x8, wqvk, wd2h,
        dist_emb, dir_emb, Wsp1, bsp1, Wsp2, bsp2, enc_tab,
        eidx, coords, deg_i, indeg_i, cellcnt, E, N);
  }
  // 2. fused output-projection weights + bias (independent)
  wfo_kernel<<<dim3(256, 4), 256, 0, stream>>>(Wf, Wo, bo, bf, wfo, bias_f);
  // 3. scans (3 independent blocks)
  scan_kernel<<<3, 1024, 0, stream>>>(indeg_i, deg_i, cellcnt, dptr, sptr, cptr, N);
  // 3b. degree-descending permutation for edge_attn scheduling
  perm_kernel<<<1, 1024, 0, stream>>>(dptr, perm, N);
  // 4. CSR scatter + edge bins + cell scatter
  scatter_kernel<<<(E + 255) / 256, 256, 0, stream>>>(eidx, coords, dptr, sptr, cptr,
                                                      fill_d, fill_s, fill_c, erec, sdst, scoord, E, N);
  // 5. node stats: spatial density + fvar
  node_stats_kernel<<<(N + 3) / 4, 256, 0, stream>>>(coords, scoord, cptr, x, x8,
                                                     sptr, sdst, sp_i, fvar, N);
  // 6. maxes
  maxred_kernel<<<1, 1024, 0, stream>>>(sptr, sp_i, fvar, maxf, N);

  const int mtiles = Mp / 128;
  // 7. density hidden layer, all scales
  h_kernel<<<dim3((N * 128 + 255) / 256, 3), 256, 0, stream>>>(sptr, sp_i, fvar, maxf,
                                                               Wd1, bd1, hbuf3, N, Mp);
  // 8. df = h @ Wd2^T + bd2 (f16), all scales
  gemm_bt_f16<<<dim3(mtiles, 2, 3), 256, 0, stream>>>(hbuf3, 128, (long)Mp * 128,
                                                      wd2h, 128, 32768, bd2, 256,
                                                      dfh3, 256, (long)Mp * 256, 128, Mp, 1,
                                                      nullptr, 0, 0, 99);
  // 9. normalize -> fp8 dfn, all scales
  norm_kernel<<<dim3((N + 3) / 4, 3), 256, 0, stream>>>(dfh3, drec3, N, Mp);
  // 10. q,v (f16) and k (fp8) in one split-output GEMM, all scales
  gemm_bt_f16<<<dim3(mtiles, 6, 3), 256, 0, stream>>>(x_h, 256, 0,
                                                      wqvk, 256, 196608, nullptr, 0,
                                                      nrec3, 512, (long)Mp * 512, 256, Mp, 1,
                                                      (unsigned char*)krec3, 256, (long)Mp * 256, 4);
  // 11. edge attention + scatter softmax + aggregate, all scales (batched, perm-scheduled)
  edge_attn<<<dim3((N + 3) / 4, 3), 256, 0, stream>>>(nrec3, krec3, drec3, erec, dptr, perm,
                                                      enc_tab, temp, aggc, N, Mp);
  // 12. fused (Wo then Wf) GEMM: out = aggc @ Wfo^T + bias_f  -> d_out f32
  gemm_bt_f16<<<dim3(mtiles, 2, 1), 256, 0, stream>>>(aggc, 768, 0,
                                                      wfo, 768, 0, bias_f, 0,
                                                      d_out, 256, 0, 768, N, 0,
                                                      nullptr, 0, 0, 99);
}

// Round 11
// 386.337 us; speedup vs baseline: 1.2311x; 1.1025x over previous
//
#include <hip/hip_runtime.h>

typedef _Float16 f16;
typedef _Float16 f16x4 __attribute__((ext_vector_type(4)));
typedef _Float16 f16x8 __attribute__((ext_vector_type(8)));
typedef float    f32x4 __attribute__((ext_vector_type(4)));
typedef float    fv2   __attribute__((ext_vector_type(2)));

__device__ __forceinline__ float4 ld4h(const f16* p) {
  f16x4 t = *(const f16x4*)p;
  return make_float4((float)t[0], (float)t[1], (float)t[2], (float)t[3]);
}

__device__ __forceinline__ float4 dec_fp8x4(unsigned u) {
  fv2 lo = __builtin_amdgcn_cvt_pk_f32_fp8(u, false);
  fv2 hi = __builtin_amdgcn_cvt_pk_f32_fp8(u, true);
  return make_float4(lo[0], lo[1], hi[0], hi[1]);
}

__device__ __forceinline__ unsigned enc_fp8x4(float a, float b, float c, float d) {
  unsigned v = 0;
  v = __builtin_amdgcn_cvt_pk_fp8_f32(a, b, v, false);
  v = __builtin_amdgcn_cvt_pk_fp8_f32(c, d, v, true);
  return v;
}

__device__ __forceinline__ void gld_lds16(const void* g, void* l) {
  __builtin_amdgcn_global_load_lds(
      (const __attribute__((address_space(1))) unsigned*)g,
      (__attribute__((address_space(3))) unsigned*)l, 16, 0, 0);
}

__device__ __forceinline__ int cell_of(const float* coords, int i) {
  int cx = (int)(coords[2 * i] * 0.02f);
  int cy = (int)(coords[2 * i + 1] * 0.02f);
  cx = cx < 0 ? 0 : (cx > 19 ? 19 : cx);
  cy = cy < 0 ? 0 : (cy > 19 ? 19 : cy);
  return cy * 20 + cx;
}

// ===================== prep: cast (blocks 0..2047) + enc tables (2048..2066) + hist (2067..) =====
// wqvk layout per scale: rows [0:256)=q, [256:512)=v, [512:768)=k
__global__ __launch_bounds__(256) void prep_kernel(
    const float* __restrict__ x, const float* __restrict__ Wq, const float* __restrict__ Wk,
    const float* __restrict__ Wv, const float* __restrict__ Wd2,
    f16* __restrict__ x_h, unsigned* __restrict__ x8, f16* __restrict__ wqvk,
    f16* __restrict__ wd2h,
    const float* __restrict__ dist_emb, const float* __restrict__ dir_emb,
    const float* __restrict__ Wsp1, const float* __restrict__ bsp1,
    const float* __restrict__ Wsp2, const float* __restrict__ bsp2,
    float* __restrict__ enc_tab,
    const int* __restrict__ eidx, const float* __restrict__ coords,
    int* deg_i, int* indeg_i, int* cellcnt, int E, int N)
{
  const int b = blockIdx.x;
  if (b < 2048) {
    const int n0 = N * 64;
    const int total = n0 + 147456 + 24576;
    for (int i = b * 256 + threadIdx.x; i < total; i += 2048 * 256) {
      int k = i;
      if (k < n0) {
        float4 v = ((const float4*)x)[k];
        f16x4 o; o[0] = (f16)v.x; o[1] = (f16)v.y; o[2] = (f16)v.z; o[3] = (f16)v.w;
        ((f16x4*)x_h)[k] = o;
        x8[k] = enc_fp8x4(v.x, v.y, v.z, v.w);
        continue;
      }
      const float4* sp; f16x4* dp;
      k -= n0;
      if (k < 147456) {
        int s = k / 49152, r = k % 49152, m = r / 16384, off = r % 16384;
        const float* w = (m == 0) ? Wq : (m == 1) ? Wk : Wv;
        int dblk = (m == 0) ? 0 : (m == 1) ? 32768 : 16384;
        sp = (const float4*)(w + s * 65536) + off;
        dp = (f16x4*)wqvk + s * 49152 + dblk + off;
      } else {
        k -= 147456;
        sp = (const float4*)Wd2 + k; dp = (f16x4*)wd2h + k;
      }
      float4 v = *sp;
      f16x4 o; o[0] = (f16)v.x; o[1] = (f16)v.y; o[2] = (f16)v.z; o[3] = (f16)v.w;
      *dp = o;
    }
  } else if (b < 2067) {
    int id = (b - 2048) * 256 + threadIdx.x;
    if (id >= 3 * 1600) return;
    int s = id / 1600, c = id % 1600, db = c >> 4, ab = c & 15;
    const float* de = dist_emb + (size_t)(s * 100 + db) * 16;
    const float* ae = dir_emb + (size_t)(s * 16 + ab) * 16;
    const float* w1 = Wsp1 + s * 1024;
    const float* b1 = bsp1 + s * 32;
    const float* w2 = Wsp2 + s * 32;
    float enc = bsp2[s];
    for (int j = 0; j < 32; ++j) {
      float a = b1[j];
      const float* wr = w1 + j * 32;
#pragma unroll
      for (int i = 0; i < 16; ++i) a += de[i] * wr[i];
#pragma unroll
      for (int i = 0; i < 16; ++i) a += ae[i] * wr[16 + i];
      enc += fmaxf(a, 0.0f) * w2[j];
    }
    enc_tab[id] = enc;
  } else {
    int e = (b - 2067) * 256 + threadIdx.x;
    if (e < E) {
      atomicAdd(&deg_i[eidx[e]], 1);
      atomicAdd(&indeg_i[eidx[E + e]], 1);
    }
    if (e < N) atomicAdd(&cellcnt[cell_of(coords, e)], 1);
  }
}

// ===================== Wfo = Wf_s @ Wo_s ; block y==3 computes fused bias =====================
__global__ __launch_bounds__(256) void wfo_kernel(
    const float* __restrict__ Wf, const float* __restrict__ Wo,
    const float* __restrict__ bo, const float* __restrict__ bf,
    f16* __restrict__ wfo, float* __restrict__ bias_f)
{
  const int j = threadIdx.x;
  if (blockIdx.y == 3) {
    if (blockIdx.x != 0) return;
    float acc = bf[j];
    const float* wr = Wf + (size_t)j * 768;
    for (int t = 0; t < 768; ++t) acc = fmaf(bo[t], wr[t], acc);
    bias_f[j] = acc;
    return;
  }
  __shared__ float wrow[256];
  const int o = blockIdx.x, s = blockIdx.y;
  wrow[j] = Wf[o * 768 + s * 256 + j];
  __syncthreads();
  const float* wo = Wo + (size_t)s * 65536 + j;
  float acc = 0.f;
#pragma unroll 8
  for (int m = 0; m < 256; ++m) acc = fmaf(wrow[m], wo[(size_t)m * 256], acc);
  wfo[(size_t)o * 768 + s * 256 + j] = (f16)acc;
}

// ===================== scans (passes 0-2) + degree-desc perm (pass 3) =====================
__global__ __launch_bounds__(1024) void scan_kernel(const int* __restrict__ indeg,
                                                    const int* __restrict__ deg,
                                                    const int* __restrict__ cellcnt,
                                                    int* dptr, int* sptr, int* cptr,
                                                    int* __restrict__ perm, int N)
{
  __shared__ int lds[1024];
  __shared__ int cnt[256], scn2[256], fill[256];
  const int tid = threadIdx.x;
  const int pass = blockIdx.x;
  if (pass == 3) {
    // counting-sort permutation by descending in-degree
    if (tid < 256) { cnt[tid] = 0; fill[tid] = 0; }
    __syncthreads();
    for (int n = tid; n < N; n += 1024) {
      int d = indeg[n];
      int key = 255 - (d > 255 ? 255 : d);
      atomicAdd(&cnt[key], 1);
    }
    __syncthreads();
    if (tid < 256) scn2[tid] = cnt[tid];
    __syncthreads();
    for (int off = 1; off < 256; off <<= 1) {
      int v = 0;
      if (tid < 256 && tid >= off) v = scn2[tid - off];
      __syncthreads();
      if (tid < 256) scn2[tid] += v;
      __syncthreads();
    }
    for (int n = tid; n < N; n += 1024) {
      int d = indeg[n];
      int key = 255 - (d > 255 ? 255 : d);
      int pos = scn2[key] - cnt[key] + atomicAdd(&fill[key], 1);
      perm[pos] = n;
    }
    return;
  }
  const int* in = (pass == 0) ? indeg : (pass == 1) ? deg : cellcnt;
  int* out = (pass == 0) ? dptr : (pass == 1) ? sptr : cptr;
  int len = (pass == 2) ? 400 : N;
  int base = tid * 16;
  int loc[16];
  int sum = 0;
#pragma unroll
  for (int j = 0; j < 16; ++j) {
    int v = (base + j < len) ? in[base + j] : 0;
    loc[j] = sum; sum += v;
  }
  lds[tid] = sum;
  __syncthreads();
  for (int off = 1; off < 1024; off <<= 1) {
    int t = (tid >= off) ? lds[tid - off] : 0;
    __syncthreads();
    lds[tid] += t;
    __syncthreads();
  }
  int prev = tid ? lds[tid - 1] : 0;
#pragma unroll
  for (int j = 0; j < 16; ++j)
    if (base + j < len) out[base + j] = prev + loc[j];
  if (tid == 1023) out[len] = lds[1023];
}

// ===================== CSR scatter + per-edge geometry bins + cell scatter =====================
__global__ __launch_bounds__(256) void scatter_kernel(
    const int* __restrict__ eidx, const float* __restrict__ coords,
    const int* __restrict__ dptr, const int* __restrict__ sptr, const int* __restrict__ cptr,
    int* fill_d, int* fill_s, int* fill_c,
    int2* __restrict__ erec, int* __restrict__ sdst, float2* __restrict__ scoord, int E, int N)
{
  int e = blockIdx.x * 256 + threadIdx.x;
  if (e < E) {
    int s = eidx[e], d = eidx[E + e];
    float rx = coords[2 * s] - coords[2 * d];
    float ry = coords[2 * s + 1] - coords[2 * d + 1];
    float dist = sqrtf(rx * rx + ry * ry);
    float ang = atan2f(ry, rx);
    int ab = (int)((ang + 3.14159265358979323846f) / 6.28318530717958647692f * 15.0f);
    ab = ab < 0 ? 0 : (ab > 15 ? 15 : ab);
    int b0 = (int)((dist / 500.0f) * 99.0f);  b0 = b0 < 0 ? 0 : (b0 > 99 ? 99 : b0);
    int b1 = (int)((dist / 1000.0f) * 99.0f); b1 = b1 < 0 ? 0 : (b1 > 99 ? 99 : b1);
    int b2 = (int)((dist / 2000.0f) * 99.0f); b2 = b2 < 0 ? 0 : (b2 > 99 ? 99 : b2);
    unsigned pb = (unsigned)b0 | ((unsigned)b1 << 7) | ((unsigned)b2 << 14) | ((unsigned)ab << 21);
    int pd = dptr[d] + atomicAdd(&fill_d[d], 1);
    erec[pd] = make_int2(s, (int)pb);
    int ps = sptr[s] + atomicAdd(&fill_s[s], 1);
    sdst[ps] = d;
  }
  if (e < N) {
    int cid = cell_of(coords, e);
    int pc = cptr[cid] + atomicAdd(&fill_c[cid], 1);
    scoord[pc] = ((const float2*)coords)[e];
  }
}

// ===================== node stats: spatial density (cells) + fvar (slot-layout), wave/node =====================
__global__ __launch_bounds__(256) void node_stats_kernel(
    const float* __restrict__ coords, const float2* __restrict__ scoord,
    const int* __restrict__ cptr,
    const float* __restrict__ x, const unsigned* __restrict__ x8,
    const int* __restrict__ sptr, const int* __restrict__ sdst,
    int* __restrict__ sp_i, float* __restrict__ fvar, int N)
{
  int wv = threadIdx.x >> 6, lane = threadIdx.x & 63;
  int node = blockIdx.x * 4 + wv;
  if (node >= N) return;

  float cx = coords[2 * node], cy = coords[2 * node + 1];
  {
    int gx = (int)(cx * 0.02f); gx = gx < 0 ? 0 : (gx > 19 ? 19 : gx);
    int gy = (int)(cy * 0.02f); gy = gy < 0 ? 0 : (gy > 19 ? 19 : gy);
    int x0 = gx > 0 ? gx - 1 : 0, x1 = gx < 19 ? gx + 1 : 19;
    int y0 = gy > 0 ? gy - 1 : 0, y1 = gy < 19 ? gy + 1 : 19;
    int cnt = 0;
    for (int r = y0; r <= y1; ++r) {
      int j0 = cptr[r * 20 + x0], j1 = cptr[r * 20 + x1 + 1];
      for (int j = j0 + lane; j < j1; j += 64) {
        float2 c = scoord[j];
        float dx = cx - c.x, dy = cy - c.y;
        cnt += (dx * dx + dy * dy <= 2500.0f) ? 1 : 0;
      }
    }
    cnt += __shfl_xor(cnt, 1);  cnt += __shfl_xor(cnt, 2);  cnt += __shfl_xor(cnt, 4);
    cnt += __shfl_xor(cnt, 8);  cnt += __shfl_xor(cnt, 16); cnt += __shfl_xor(cnt, 32);
    if (lane == 0) sp_i[node] = cnt;
  }

  const int slot = lane >> 3, w = lane & 7;
  float sum[32];
#pragma unroll
  for (int i = 0; i < 32; ++i) sum[i] = 0.f;
  int e0 = sptr[node], e1 = sptr[node + 1];
  int nit = (e1 - e0 + 7) >> 3;
  for (int it = 0; it < nit; ++it) {
    int e = e0 + it * 8 + slot;
    bool valid = e < e1;
    int dd = sdst[valid ? e : e1 - 1];
    const unsigned* xp = x8 + dd * 64 + w * 8;
    uint4 a = *(const uint4*)xp;
    uint4 b = *(const uint4*)(xp + 4);
    float vm = valid ? 1.f : 0.f;
    unsigned wd[8] = {a.x, a.y, a.z, a.w, b.x, b.y, b.z, b.w};
#pragma unroll
    for (int k = 0; k < 8; ++k) {
      float4 f = dec_fp8x4(wd[k]);
      sum[k*4+0] = fmaf(vm, f.x, sum[k*4+0]);
      sum[k*4+1] = fmaf(vm, f.y, sum[k*4+1]);
      sum[k*4+2] = fmaf(vm, f.z, sum[k*4+2]);
      sum[k*4+3] = fmaf(vm, f.w, sum[k*4+3]);
    }
  }
#pragma unroll
  for (int i = 0; i < 32; ++i) {
    sum[i] += __shfl_xor(sum[i], 8);
    sum[i] += __shfl_xor(sum[i], 16);
    sum[i] += __shfl_xor(sum[i], 32);
  }
  float rcnt = 1.0f / fmaxf((float)(e1 - e0), 1.0f);
  const float4* xp4 = (const float4*)(x + (size_t)node * 256 + w * 32);
  float ss = 0.f;
#pragma unroll
  for (int k = 0; k < 8; ++k) {
    float4 xm = xp4[k];
    float d0 = xm.x - sum[k*4+0] * rcnt;
    float d1 = xm.y - sum[k*4+1] * rcnt;
    float d2 = xm.z - sum[k*4+2] * rcnt;
    float d3 = xm.w - sum[k*4+3] * rcnt;
    ss += d0*d0 + d1*d1 + d2*d2 + d3*d3;
  }
  ss += __shfl_xor(ss, 1);  ss += __shfl_xor(ss, 2);  ss += __shfl_xor(ss, 4);
  ss += __shfl_xor(ss, 8);  ss += __shfl_xor(ss, 16); ss += __shfl_xor(ss, 32);
  if (lane == 0) fvar[node] = sqrtf(ss * 0.125f);
}

// ===================== global maxes: single block, LDS tree =====================
__global__ __launch_bounds__(1024) void maxred_kernel(
    const int* __restrict__ sptr, const int* __restrict__ sp_i,
    const float* __restrict__ fvar, float* __restrict__ maxf, int N)
{
  __shared__ float l0[1024], l1[1024], l2[1024];
  int tid = threadIdx.x;
  float m0 = 0.f, m1 = 0.f, m2 = 0.f;
  for (int i = tid; i < N; i += 1024) {
    m0 = fmaxf(m0, (float)(sptr[i + 1] - sptr[i]));
    m1 = fmaxf(m1, (float)(sp_i[i] - 1));
    m2 = fmaxf(m2, fvar[i]);
  }
  l0[tid] = m0; l1[tid] = m1; l2[tid] = m2;
  __syncthreads();
  for (int off = 512; off > 0; off >>= 1) {
    if (tid < off) {
      l0[tid] = fmaxf(l0[tid], l0[tid + off]);
      l1[tid] = fmaxf(l1[tid], l1[tid + off]);
      l2[tid] = fmaxf(l2[tid], l2[tid + off]);
    }
    __syncthreads();
  }
  if (tid == 0) { maxf[0] = l0[0]; maxf[1] = l1[0]; maxf[2] = l2[0]; }
}

// ===================== per-scale hidden h = relu(dens @ Wd1^T + bd1), batched over scales =====================
__global__ __launch_bounds__(256) void h_kernel(
    const int* __restrict__ sptr, const int* __restrict__ sp_i, const float* __restrict__ fvar,
    const float* __restrict__ maxf, const float* __restrict__ Wd1,
    const float* __restrict__ bd1, f16* __restrict__ hbuf, int N, int Mp)
{
  int id = blockIdx.x * 256 + threadIdx.x;
  if (id >= N * 128) return;
  int s = blockIdx.y;
  int node = id >> 7, j = id & 127;
  float dm = maxf[0] + 1e-8f;
  float sm = maxf[1] + 1e-8f;
  float fm = maxf[2] + 1e-8f;
  float d0 = (float)(sptr[node + 1] - sptr[node]) / dm;
  float d1 = (float)(sp_i[node] - 1) / sm;
  float d2 = fvar[node] / fm;
  const float* wr = Wd1 + s * 384 + j * 3;
  float h = fmaxf(wr[0] * d0 + wr[1] * d1 + wr[2] * d2 + bd1[s * 128 + j], 0.0f);
  hbuf[(size_t)s * Mp * 128 + (size_t)node * 128 + j] = (f16)h;
}

// ===================== fp16 MFMA GEMM, scale-batched, XOR-swizzled LDS, split fp8 output =====
__global__ __launch_bounds__(256) void gemm_bt_f16(
    const f16* __restrict__ A, int lda, long sA,
    const f16* __restrict__ B, int ldb, long sB,
    const float* __restrict__ bias, int sBias,
    void* __restrict__ Cv, int ldc, long sC, int K, int Mstore, int outMode,
    unsigned char* __restrict__ Cv2, int ldc2, long sC2, int ysplit)
{
  __shared__ f16 As[128 * 64];
  __shared__ f16 Bs[128 * 64];
  const int s = blockIdx.z;
  const int tid = threadIdx.x;
  const int lane = tid & 63;
  const int w = tid >> 6;
  const int wr = (w >> 1) * 64, wc = (w & 1) * 64;
  const int srow = tid >> 3;
  const int scol = (((tid & 7) ^ (srow & 7))) * 8;   // pre-swizzled source (rule #21)
  const f16* Ab = A + (size_t)s * sA + (size_t)(blockIdx.x * 128 + srow) * lda + scol;
  const f16* Bb = B + (size_t)s * sB + (size_t)(blockIdx.y * 128 + srow) * ldb + scol;
  char* Asl = (char*)As + tid * 16;
  char* Bsl = (char*)Bs + tid * 16;

  f32x4 acc[4][4] = {};

  for (int kt = 0; kt < K; kt += 64) {
    __syncthreads();
#pragma unroll
    for (int i = 0; i < 4; ++i) {
      gld_lds16(Ab + (size_t)i * 32 * lda + kt, Asl + i * 4096);
      gld_lds16(Bb + (size_t)i * 32 * ldb + kt, Bsl + i * 4096);
    }
    __syncthreads();
#pragma unroll
    for (int kq = 0; kq < 2; ++kq) {
      const int krd = kq * 32 + (lane >> 4) * 8;
      const int kc = krd >> 3;
      f16x8 af[4], bfr[4];
#pragma unroll
      for (int t = 0; t < 4; ++t) {
        const int ra = wr + t * 16 + (lane & 15);
        const int rb = wc + t * 16 + (lane & 15);
        af[t]  = *(const f16x8*)&As[ra * 64 + (kc ^ (ra & 7)) * 8];
        bfr[t] = *(const f16x8*)&Bs[rb * 64 + (kc ^ (rb & 7)) * 8];
      }
#pragma unroll
      for (int mi = 0; mi < 4; ++mi)
#pragma unroll
        for (int ni = 0; ni < 4; ++ni)
          acc[mi][ni] = __builtin_amdgcn_mfma_f32_16x16x32_f16(af[mi], bfr[ni], acc[mi][ni], 0, 0, 0);
    }
  }

  const int r0 = (lane >> 4) << 2;
  const int c0 = lane & 15;
  const bool f8p = ((int)blockIdx.y >= ysplit);
  const int cbase = f8p ? ((int)blockIdx.y - ysplit) * 128 : (int)blockIdx.y * 128;
#pragma unroll
  for (int mi = 0; mi < 4; ++mi) {
#pragma unroll
    for (int ni = 0; ni < 4; ++ni) {
      int col = cbase + wc + ni * 16 + c0;
      float bv = (!f8p && bias) ? bias[s * sBias + col] : 0.0f;
#pragma unroll
      for (int r = 0; r < 4; ++r) {
        int row = blockIdx.x * 128 + wr + mi * 16 + r0 + r;
        if (row < Mstore) {
          float v = acc[mi][ni][r] + bv;
          if (f8p) {
            unsigned pk = __builtin_amdgcn_cvt_pk_fp8_f32(v, v, 0u, false);
            Cv2[(size_t)s * sC2 + (size_t)row * ldc2 + col] = (unsigned char)(pk & 0xffu);
          } else if (outMode == 1) {
            ((f16*)Cv)[(size_t)s * sC + (size_t)row * ldc + col] = (f16)v;
          } else {
            ((float*)Cv)[(size_t)s * sC + (size_t)row * ldc + col] = v;
          }
        }
      }
    }
  }
}

// ===================== normalize df rows -> dfn (fp8), batched over scales =====================
__global__ __launch_bounds__(256) void norm_kernel(const f16* __restrict__ dfh,
                                                   unsigned* __restrict__ drec8, int N, int Mp)
{
  int wv = threadIdx.x >> 6, lane = threadIdx.x & 63;
  int node = blockIdx.x * 4 + wv;
  if (node >= N) return;
  int s = blockIdx.y;
  float4 d = ld4h(dfh + (size_t)s * Mp * 256 + (size_t)node * 256 + lane * 4);
  float ss = d.x * d.x + d.y * d.y + d.z * d.z + d.w * d.w;
  ss += __shfl_xor(ss, 1);  ss += __shfl_xor(ss, 2);  ss += __shfl_xor(ss, 4);
  ss += __shfl_xor(ss, 8);  ss += __shfl_xor(ss, 16); ss += __shfl_xor(ss, 32);
  float rn = 1.0f / fmaxf(sqrtf(ss), 1e-8f);
  drec8[(size_t)s * Mp * 64 + node * 64 + lane] = enc_fp8x4(d.x * rn, d.y * rn, d.z * rn, d.w * rn);
}

// ===================== edge attention: wave/node, slot(4) x sub(16: head x half) =====
// nrec row (per node, f16, 512): [0:256)=q [256:512)=v ; krec8/drec8: fp8 (64 u32 words per node)
// aggc: concat layout, row stride 768, scale s cols [s*256, s*256+256)
__global__ __launch_bounds__(256) void edge_attn(
    const f16* __restrict__ nrec0, const unsigned* __restrict__ krec0,
    const unsigned* __restrict__ drec0, const int2* __restrict__ erec,
    const int* __restrict__ dptr, const int* __restrict__ perm,
    const float* __restrict__ enc_tab, const float* __restrict__ temp,
    f16* __restrict__ aggc, int N, int Mp)
{
  int wv = threadIdx.x >> 6, lane = threadIdx.x & 63;
  int node = blockIdx.x * 4 + wv;
  if (node >= N) return;
  node = perm[node];   // degree-descending schedule
  const int s = blockIdx.y;
  const int sshift = 7 * s;
  const f16* nrec = nrec0 + (size_t)s * Mp * 512;
  const unsigned* krec8 = krec0 + (size_t)s * Mp * 64;
  const unsigned* drec8 = drec0 + (size_t)s * Mp * 64;
  const float* enc_s = enc_tab + s * 1600;

  const int slot = lane >> 4;   // edge slot 0..3
  const int sub  = lane & 15;   // head(3b)<<1 | half
  const int hd   = sub >> 1;
  const int half = sub & 1;
  const int doff = hd * 8 + half * 4;    // u32-word offset of this lane's 16 dims (fp8)
  const int voff = hd * 32 + half * 16;  // f16 offset of this lane's 16 dims

  // q (f32) for this lane's 16 dims
  float qf[16];
  {
    const f16* qp = nrec + (size_t)node * 512 + voff;
    f16x8 a = *(const f16x8*)qp;
    f16x8 b = *(const f16x8*)(qp + 8);
#pragma unroll
    for (int j = 0; j < 8; ++j) { qf[j] = (float)a[j]; qf[8 + j] = (float)b[j]; }
  }
  uint4 diw = *(const uint4*)(drec8 + node * 64 + doff);
  const float inv_th = 0.17677669529663687f / temp[s * 8 + hd];

  float m = -1e30f, z = 0.f;
  float acc[16];
#pragma unroll
  for (int i = 0; i < 16; ++i) acc[i] = 0.f;

  int e0 = dptr[node], e1 = dptr[node + 1];
  int nit = (e1 - e0 + 3) >> 2;
  for (int it = 0; it < nit; ++it) {
    int e = e0 + it * 4 + slot;
    bool valid = e < e1;
    int2 rec = erec[valid ? e : e1 - 1];
    int src = rec.x;
    unsigned pb = (unsigned)rec.y;
    uint4 kwv = *(const uint4*)(krec8 + src * 64 + doff);
    uint4 dwv = *(const uint4*)(drec8 + src * 64 + doff);
    const f16* vp = nrec + (size_t)src * 512 + 256 + voff;
    f16x8 vs0 = *(const f16x8*)vp;
    f16x8 vs1 = *(const f16x8*)(vp + 8);
    float enc = enc_s[((pb >> sshift) & 127u) * 16 + (pb >> 21)];

    unsigned kw[4] = {kwv.x, kwv.y, kwv.z, kwv.w};
    unsigned dw[4] = {dwv.x, dwv.y, dwv.z, dwv.w};
    unsigned di[4] = {diw.x, diw.y, diw.z, diw.w};
    float qk0 = 0.f, qk1 = 0.f, ds0 = 0.f, ds1 = 0.f;
#pragma unroll
    for (int w = 0; w < 4; ++w) {
      float4 kf = dec_fp8x4(kw[w]);
      qk0 = fmaf(qf[w*4+0], kf.x, qk0);
      qk1 = fmaf(qf[w*4+1], kf.y, qk1);
      qk0 = fmaf(qf[w*4+2], kf.z, qk0);
      qk1 = fmaf(qf[w*4+3], kf.w, qk1);
      float4 df = dec_fp8x4(dw[w]);
      float4 dd = dec_fp8x4(di[w]);
      ds0 = fmaf(dd.x, df.x, ds0);
      ds1 = fmaf(dd.y, df.y, ds1);
      ds0 = fmaf(dd.z, df.z, ds0);
      ds1 = fmaf(dd.w, df.w, ds1);
    }
    float qk = qk0 + qk1;
    float ds = ds0 + ds1;
    qk += __shfl_xor(qk, 1);                    // merge halves -> full head dot
    ds += __shfl_xor(ds, 1); ds += __shfl_xor(ds, 2);
    ds += __shfl_xor(ds, 4); ds += __shfl_xor(ds, 8);   // full-D dot across 16 sub-lanes

    float sc = (qk * inv_th + enc) * (1.0f + 0.5f * ds);
    sc = valid ? sc : -1e30f;
    if (__any(sc > m + 8.0f)) {
      float mn = fmaxf(m, sc);
      float rs = __expf(m - mn);
      z *= rs;
#pragma unroll
      for (int i = 0; i < 16; ++i) acc[i] *= rs;
      m = mn;
    }
    float p = __expf(sc - m) * (valid ? 1.0f : 0.0f);
    z += p;
#pragma unroll
    for (int j = 0; j < 8; ++j) acc[j]     = fmaf(p, (float)vs0[j], acc[j]);
#pragma unroll
    for (int j = 0; j < 8; ++j) acc[8 + j] = fmaf(p, (float)vs1[j], acc[8 + j]);
  }

  // merge the 4 slots (lane bits 4..5), same sub
  float M = m;
  M = fmaxf(M, __shfl_xor(M, 16));
  M = fmaxf(M, __shfl_xor(M, 32));
  float f = __expf(m - M);
  z *= f;
  z += __shfl_xor(z, 16); z += __shfl_xor(z, 32);
#pragma unroll
  for (int i = 0; i < 16; ++i) {
    float a = acc[i] * f;
    a += __shfl_xor(a, 16); a += __shfl_xor(a, 32);
    acc[i] = a;
  }
  float rz = 1.0f / (z + 1e-16f);
  if (slot == 0) {
    f16* op = aggc + (size_t)node * 768 + s * 256 + voff;
    f16x8 o0, o1;
#pragma unroll
    for (int j = 0; j < 8; ++j) { o0[j] = (f16)(acc[j] * rz); o1[j] = (f16)(acc[8 + j] * rz); }
    *(f16x8*)op = o0;
    *(f16x8*)(op + 8) = o1;
  }
}

// ===================== host launcher =====================
extern "C" void kernel_launch(void* const* d_in, const int* in_sizes, int n_in,
                              void* d_out, int out_size, void* d_ws, size_t ws_size,
                              hipStream_t stream)
{
  const float* x      = (const float*)d_in[0];
  const float* coords = (const float*)d_in[1];
  const int*   eidx   = (const int*)  d_in[2];
  const float* Wq   = (const float*)d_in[3];
  const float* Wk   = (const float*)d_in[4];
  const float* Wv   = (const float*)d_in[5];
  const float* Wo   = (const float*)d_in[6];
  const float* bo   = (const float*)d_in[7];
  const float* temp = (const float*)d_in[8];
  const float* dist_emb = (const float*)d_in[9];
  const float* dir_emb  = (const float*)d_in[10];
  const float* Wsp1 = (const float*)d_in[11];
  const float* bsp1 = (const float*)d_in[12];
  const float* Wsp2 = (const float*)d_in[13];
  const float* bsp2 = (const float*)d_in[14];
  const float* Wd1  = (const float*)d_in[15];
  const float* bd1  = (const float*)d_in[16];
  const float* Wd2  = (const float*)d_in[17];
  const float* bd2  = (const float*)d_in[18];
  const float* Wf   = (const float*)d_in[19];
  const float* bf   = (const float*)d_in[20];
  (void)n_in; (void)out_size; (void)ws_size;

  const int N  = in_sizes[0] / 256;
  const int E  = in_sizes[2] / 2;
  const int Mp = ((N + 127) / 128) * 128;

  char* p = (char*)d_ws;
  auto alloc = [&](size_t b) -> void* {
    void* r = (void*)p;
    p += (b + 255) & ~(size_t)255;
    return r;
  };

  f16*      x_h   = (f16*)     alloc((size_t)Mp * 256 * 2);
  unsigned* x8    = (unsigned*)alloc((size_t)Mp * 256);
  f16*      nrec3 = (f16*)     alloc((size_t)3 * Mp * 512 * 2);  // q|v per node per scale
  unsigned* krec3 = (unsigned*)alloc((size_t)3 * Mp * 256);
  unsigned* drec3 = (unsigned*)alloc((size_t)3 * Mp * 256);
  f16*      hbuf3 = (f16*)     alloc((size_t)3 * Mp * 128 * 2);
  f16*      dfh3  = (f16*)     alloc((size_t)3 * Mp * 256 * 2);
  f16*      aggc  = (f16*)     alloc((size_t)Mp * 768 * 2);      // concat agg, row stride 768
  f16*      wqvk  = (f16*)     alloc((size_t)3 * 768 * 256 * 2);
  f16*      wfo   = (f16*)     alloc((size_t)256 * 768 * 2);
  float*    bias_f = (float*)  alloc(256 * 4);
  f16*      wd2h  = (f16*)     alloc((size_t)3 * 256 * 128 * 2);
  float*    enc_tab = (float*) alloc((size_t)3 * 1600 * 4);
  int*    dptr = (int*)   alloc((size_t)(N + 1) * 4);
  int*    sptr = (int*)   alloc((size_t)(N + 1) * 4);
  int*    cptr = (int*)   alloc((size_t)401 * 4);
  int*    perm = (int*)   alloc((size_t)N * 4);
  int2*   erec = (int2*)  alloc((size_t)E * 8);
  int*    sdst = (int*)   alloc((size_t)E * 4);
  float2* scoord = (float2*)alloc((size_t)N * 8);
  float*  fvar = (float*) alloc((size_t)N * 4);
  int*    sp_i = (int*)   alloc((size_t)N * 4);
  float*  maxf = (float*) alloc(4 * 4);
  // ---- zeroed-every-call block ----
  char* z0 = p;
  int* deg_i   = (int*)alloc((size_t)N * 4);
  int* indeg_i = (int*)alloc((size_t)N * 4);
  int* fill_d  = (int*)alloc((size_t)N * 4);
  int* fill_s  = (int*)alloc((size_t)N * 4);
  int* cellcnt = (int*)alloc(400 * 4);
  int* fill_c  = (int*)alloc(400 * 4);
  size_t zbytes = (size_t)(p - z0);
  hipMemsetAsync(z0, 0, zbytes, stream);

  // 1. prep: cast + enc tables + histograms (one dispatch)
  {
    int histBlocks = (E + 255) / 256;
    prep_kernel<<<2067 + histBlocks, 256, 0, stream>>>(
        x, Wq, Wk, Wv, Wd2, x_h, x8, wqvk, wd2h,
        dist_emb, dir_emb, Wsp1, bsp1, Wsp2, bsp2, enc_tab,
        eidx, coords, deg_i, indeg_i, cellcnt, E, N);
  }
  // 2. fused output-projection weights + bias (independent)
  wfo_kernel<<<dim3(256, 4), 256, 0, stream>>>(Wf, Wo, bo, bf, wfo, bias_f);
  // 3. scans + degree-desc perm (4 independent blocks)
  scan_kernel<<<4, 1024, 0, stream>>>(indeg_i, deg_i, cellcnt, dptr, sptr, cptr, perm, N);
  // 4. CSR scatter + edge bins + cell scatter
  scatter_kernel<<<(E + 255) / 256, 256, 0, stream>>>(eidx, coords, dptr, sptr, cptr,
                                                      fill_d, fill_s, fill_c, erec, sdst, scoord, E, N);
  // 5. node stats: spatial density + fvar
  node_stats_kernel<<<(N + 3) / 4, 256, 0, stream>>>(coords, scoord, cptr, x, x8,
                                                     sptr, sdst, sp_i, fvar, N);
  // 6. maxes
  maxred_kernel<<<1, 1024, 0, stream>>>(sptr, sp_i, fvar, maxf, N);

  const int mtiles = Mp / 128;
  // 7. density hidden layer, all scales
  h_kernel<<<dim3((N * 128 + 255) / 256, 3), 256, 0, stream>>>(sptr, sp_i, fvar, maxf,
                                                               Wd1, bd1, hbuf3, N, Mp);
  // 8. df = h @ Wd2^T + bd2 (f16), all scales
  gemm_bt_f16<<<dim3(mtiles, 2, 3), 256, 0, stream>>>(hbuf3, 128, (long)Mp * 128,
                                                      wd2h, 128, 32768, bd2, 256,
                                                      dfh3, 256, (long)Mp * 256, 128, Mp, 1,
                                                      nullptr, 0, 0, 99);
  // 9. normalize -> fp8 dfn, all scales
  norm_kernel<<<dim3((N + 3) / 4, 3), 256, 0, stream>>>(dfh3, drec3, N, Mp);
  // 10. q,v (f16) and k (fp8) in one split-output GEMM, all scales
  gemm_bt_f16<<<dim3(mtiles, 6, 3), 256, 0, stream>>>(x_h, 256, 0,
                                                      wqvk, 256, 196608, nullptr, 0,
                                                      nrec3, 512, (long)Mp * 512, 256, Mp, 1,
                                                      (unsigned char*)krec3, 256, (long)Mp * 256, 4);
  // 11. edge attention + scatter softmax + aggregate (slot4 x sub16 layout)
  edge_attn<<<dim3((N + 3) / 4, 3), 256, 0, stream>>>(nrec3, krec3, drec3, erec, dptr, perm,
                                                      enc_tab, temp, aggc, N, Mp);
  // 12. fused (Wo then Wf) GEMM: out = aggc @ Wfo^T + bias_f  -> d_out f32
  gemm_bt_f16<<<dim3(mtiles, 2, 1), 256, 0, stream>>>(aggc, 768, 0,
                                                      wfo, 768, 0, bias_f, 0,
                                                      d_out, 256, 0, 768, N, 0,
                                                      nullptr, 0, 0, 99);
}

// Round 12
// 336.275 us; speedup vs baseline: 1.4144x; 1.1489x over previous
//
#include <hip/hip_runtime.h>

typedef _Float16 f16;
typedef _Float16 f16x4 __attribute__((ext_vector_type(4)));
typedef _Float16 f16x8 __attribute__((ext_vector_type(8)));
typedef float    f32x4 __attribute__((ext_vector_type(4)));
typedef float    fv2   __attribute__((ext_vector_type(2)));

__device__ __forceinline__ float4 ld4h(const f16* p) {
  f16x4 t = *(const f16x4*)p;
  return make_float4((float)t[0], (float)t[1], (float)t[2], (float)t[3]);
}

__device__ __forceinline__ float4 dec_fp8x4(unsigned u) {
  fv2 lo = __builtin_amdgcn_cvt_pk_f32_fp8(u, false);
  fv2 hi = __builtin_amdgcn_cvt_pk_f32_fp8(u, true);
  return make_float4(lo[0], lo[1], hi[0], hi[1]);
}

__device__ __forceinline__ unsigned enc_fp8x4(float a, float b, float c, float d) {
  unsigned v = 0;
  v = __builtin_amdgcn_cvt_pk_fp8_f32(a, b, v, false);
  v = __builtin_amdgcn_cvt_pk_fp8_f32(c, d, v, true);
  return v;
}

__device__ __forceinline__ void gld_lds16(const void* g, void* l) {
  __builtin_amdgcn_global_load_lds(
      (const __attribute__((address_space(1))) unsigned*)g,
      (__attribute__((address_space(3))) unsigned*)l, 16, 0, 0);
}

__device__ __forceinline__ int cell_of(const float* coords, int i) {
  int cx = (int)(coords[2 * i] * 0.02f);
  int cy = (int)(coords[2 * i + 1] * 0.02f);
  cx = cx < 0 ? 0 : (cx > 19 ? 19 : cx);
  cy = cy < 0 ? 0 : (cy > 19 ? 19 : cy);
  return cy * 20 + cx;
}

// ===== prep: cast | enc tables | hist | wfo | biasf (block-range partitioned) =====
// wqvk layout per scale: rows [0:256)=q, [256:512)=v, [512:768)=k
__global__ __launch_bounds__(256) void prep_kernel(
    const float* __restrict__ x, const float* __restrict__ Wq, const float* __restrict__ Wk,
    const float* __restrict__ Wv, const float* __restrict__ Wd2,
    f16* __restrict__ x_h, unsigned* __restrict__ x8, f16* __restrict__ wqvk,
    f16* __restrict__ wd2h,
    const float* __restrict__ dist_emb, const float* __restrict__ dir_emb,
    const float* __restrict__ Wsp1, const float* __restrict__ bsp1,
    const float* __restrict__ Wsp2, const float* __restrict__ bsp2,
    float* __restrict__ enc_tab,
    const int* __restrict__ eidx, const float* __restrict__ coords,
    int* deg_i, int* indeg_i, int* cellcnt,
    const float* __restrict__ Wf, const float* __restrict__ Wo,
    const float* __restrict__ bo, const float* __restrict__ bf,
    f16* __restrict__ wfo, float* __restrict__ bias_f,
    int E, int N, int hb)
{
  const int b = blockIdx.x;
  if (b < 2048) {
    const int n0 = N * 64;
    const int total = n0 + 147456 + 24576;
    for (int i = b * 256 + threadIdx.x; i < total; i += 2048 * 256) {
      int k = i;
      if (k < n0) {
        float4 v = ((const float4*)x)[k];
        f16x4 o; o[0] = (f16)v.x; o[1] = (f16)v.y; o[2] = (f16)v.z; o[3] = (f16)v.w;
        ((f16x4*)x_h)[k] = o;
        x8[k] = enc_fp8x4(v.x, v.y, v.z, v.w);
        continue;
      }
      const float4* sp; f16x4* dp;
      k -= n0;
      if (k < 147456) {
        int s = k / 49152, r = k % 49152, m = r / 16384, off = r % 16384;
        const float* w = (m == 0) ? Wq : (m == 1) ? Wk : Wv;
        int dblk = (m == 0) ? 0 : (m == 1) ? 32768 : 16384;
        sp = (const float4*)(w + s * 65536) + off;
        dp = (f16x4*)wqvk + s * 49152 + dblk + off;
      } else {
        k -= 147456;
        sp = (const float4*)Wd2 + k; dp = (f16x4*)wd2h + k;
      }
      float4 v = *sp;
      f16x4 o; o[0] = (f16)v.x; o[1] = (f16)v.y; o[2] = (f16)v.z; o[3] = (f16)v.w;
      *dp = o;
    }
  } else if (b < 2067) {
    int id = (b - 2048) * 256 + threadIdx.x;
    if (id >= 3 * 1600) return;
    int s = id / 1600, c = id % 1600, db = c >> 4, ab = c & 15;
    const float* de = dist_emb + (size_t)(s * 100 + db) * 16;
    const float* ae = dir_emb + (size_t)(s * 16 + ab) * 16;
    const float* w1 = Wsp1 + s * 1024;
    const float* b1 = bsp1 + s * 32;
    const float* w2 = Wsp2 + s * 32;
    float enc = bsp2[s];
    for (int j = 0; j < 32; ++j) {
      float a = b1[j];
      const float* wr = w1 + j * 32;
#pragma unroll
      for (int i = 0; i < 16; ++i) a += de[i] * wr[i];
#pragma unroll
      for (int i = 0; i < 16; ++i) a += ae[i] * wr[16 + i];
      enc += fmaxf(a, 0.0f) * w2[j];
    }
    enc_tab[id] = enc;
  } else if (b < 2067 + hb) {
    int e = (b - 2067) * 256 + threadIdx.x;
    if (e < E) {
      atomicAdd(&deg_i[eidx[e]], 1);
      atomicAdd(&indeg_i[eidx[E + e]], 1);
    }
    if (e < N) atomicAdd(&cellcnt[cell_of(coords, e)], 1);
  } else if (b < 2067 + hb + 768) {
    // Wfo = Wf_s @ Wo_s
    __shared__ float wrow[256];
    int idx = b - (2067 + hb);
    int s = idx >> 8, o = idx & 255;
    int j = threadIdx.x;
    wrow[j] = Wf[o * 768 + s * 256 + j];
    __syncthreads();
    const float* wo = Wo + (size_t)s * 65536 + j;
    float acc = 0.f;
#pragma unroll 8
    for (int m = 0; m < 256; ++m) acc = fmaf(wrow[m], wo[(size_t)m * 256], acc);
    wfo[(size_t)o * 768 + s * 256 + j] = (f16)acc;
  } else {
    // fused bias
    int j = threadIdx.x;
    float acc = bf[j];
    const float* wr = Wf + (size_t)j * 768;
    for (int t = 0; t < 768; ++t) acc = fmaf(bo[t], wr[t], acc);
    bias_f[j] = acc;
  }
}

// ===================== scans (passes 0-2) + degree-desc perm (pass 3) =====================
__global__ __launch_bounds__(1024) void scan_kernel(const int* __restrict__ indeg,
                                                    const int* __restrict__ deg,
                                                    const int* __restrict__ cellcnt,
                                                    int* dptr, int* sptr, int* cptr,
                                                    int* __restrict__ perm, int N)
{
  __shared__ int lds[1024];
  __shared__ int cnt[256], scn2[256], fill[256];
  const int tid = threadIdx.x;
  const int pass = blockIdx.x;
  if (pass == 3) {
    if (tid < 256) { cnt[tid] = 0; fill[tid] = 0; }
    __syncthreads();
    for (int n = tid; n < N; n += 1024) {
      int d = indeg[n];
      int key = 255 - (d > 255 ? 255 : d);
      atomicAdd(&cnt[key], 1);
    }
    __syncthreads();
    if (tid < 256) scn2[tid] = cnt[tid];
    __syncthreads();
    for (int off = 1; off < 256; off <<= 1) {
      int v = 0;
      if (tid < 256 && tid >= off) v = scn2[tid - off];
      __syncthreads();
      if (tid < 256) scn2[tid] += v;
      __syncthreads();
    }
    for (int n = tid; n < N; n += 1024) {
      int d = indeg[n];
      int key = 255 - (d > 255 ? 255 : d);
      int pos = scn2[key] - cnt[key] + atomicAdd(&fill[key], 1);
      perm[pos] = n;
    }
    return;
  }
  const int* in = (pass == 0) ? indeg : (pass == 1) ? deg : cellcnt;
  int* out = (pass == 0) ? dptr : (pass == 1) ? sptr : cptr;
  int len = (pass == 2) ? 400 : N;
  int base = tid * 16;
  int loc[16];
  int sum = 0;
#pragma unroll
  for (int j = 0; j < 16; ++j) {
    int v = (base + j < len) ? in[base + j] : 0;
    loc[j] = sum; sum += v;
  }
  lds[tid] = sum;
  __syncthreads();
  for (int off = 1; off < 1024; off <<= 1) {
    int t = (tid >= off) ? lds[tid - off] : 0;
    __syncthreads();
    lds[tid] += t;
    __syncthreads();
  }
  int prev = tid ? lds[tid - 1] : 0;
#pragma unroll
  for (int j = 0; j < 16; ++j)
    if (base + j < len) out[base + j] = prev + loc[j];
  if (tid == 1023) out[len] = lds[1023];
}

// ===================== CSR scatter + per-edge geometry bins + cell scatter =====================
__global__ __launch_bounds__(256) void scatter_kernel(
    const int* __restrict__ eidx, const float* __restrict__ coords,
    const int* __restrict__ dptr, const int* __restrict__ sptr, const int* __restrict__ cptr,
    int* fill_d, int* fill_s, int* fill_c,
    int2* __restrict__ erec, int* __restrict__ sdst, float2* __restrict__ scoord, int E, int N)
{
  int e = blockIdx.x * 256 + threadIdx.x;
  if (e < E) {
    int s = eidx[e], d = eidx[E + e];
    float rx = coords[2 * s] - coords[2 * d];
    float ry = coords[2 * s + 1] - coords[2 * d + 1];
    float dist = sqrtf(rx * rx + ry * ry);
    float ang = atan2f(ry, rx);
    int ab = (int)((ang + 3.14159265358979323846f) / 6.28318530717958647692f * 15.0f);
    ab = ab < 0 ? 0 : (ab > 15 ? 15 : ab);
    int b0 = (int)((dist / 500.0f) * 99.0f);  b0 = b0 < 0 ? 0 : (b0 > 99 ? 99 : b0);
    int b1 = (int)((dist / 1000.0f) * 99.0f); b1 = b1 < 0 ? 0 : (b1 > 99 ? 99 : b1);
    int b2 = (int)((dist / 2000.0f) * 99.0f); b2 = b2 < 0 ? 0 : (b2 > 99 ? 99 : b2);
    unsigned pb = (unsigned)b0 | ((unsigned)b1 << 7) | ((unsigned)b2 << 14) | ((unsigned)ab << 21);
    int pd = dptr[d] + atomicAdd(&fill_d[d], 1);
    erec[pd] = make_int2(s, (int)pb);
    int ps = sptr[s] + atomicAdd(&fill_s[s], 1);
    sdst[ps] = d;
  }
  if (e < N) {
    int cid = cell_of(coords, e);
    int pc = cptr[cid] + atomicAdd(&fill_c[cid], 1);
    scoord[pc] = ((const float2*)coords)[e];
  }
}

// ===================== node stats: spatial density (cells) + fvar (slot-layout), wave/node =====================
__global__ __launch_bounds__(256) void node_stats_kernel(
    const float* __restrict__ coords, const float2* __restrict__ scoord,
    const int* __restrict__ cptr,
    const float* __restrict__ x, const unsigned* __restrict__ x8,
    const int* __restrict__ sptr, const int* __restrict__ sdst,
    int* __restrict__ sp_i, float* __restrict__ fvar, int N)
{
  int wv = threadIdx.x >> 6, lane = threadIdx.x & 63;
  int node = blockIdx.x * 4 + wv;
  if (node >= N) return;

  float cx = coords[2 * node], cy = coords[2 * node + 1];
  {
    int gx = (int)(cx * 0.02f); gx = gx < 0 ? 0 : (gx > 19 ? 19 : gx);
    int gy = (int)(cy * 0.02f); gy = gy < 0 ? 0 : (gy > 19 ? 19 : gy);
    int x0 = gx > 0 ? gx - 1 : 0, x1 = gx < 19 ? gx + 1 : 19;
    int y0 = gy > 0 ? gy - 1 : 0, y1 = gy < 19 ? gy + 1 : 19;
    int cnt = 0;
    for (int r = y0; r <= y1; ++r) {
      int j0 = cptr[r * 20 + x0], j1 = cptr[r * 20 + x1 + 1];
      for (int j = j0 + lane; j < j1; j += 64) {
        float2 c = scoord[j];
        float dx = cx - c.x, dy = cy - c.y;
        cnt += (dx * dx + dy * dy <= 2500.0f) ? 1 : 0;
      }
    }
    cnt += __shfl_xor(cnt, 1);  cnt += __shfl_xor(cnt, 2);  cnt += __shfl_xor(cnt, 4);
    cnt += __shfl_xor(cnt, 8);  cnt += __shfl_xor(cnt, 16); cnt += __shfl_xor(cnt, 32);
    if (lane == 0) sp_i[node] = cnt;
  }

  const int slot = lane >> 3, w = lane & 7;
  float sum[32];
#pragma unroll
  for (int i = 0; i < 32; ++i) sum[i] = 0.f;
  int e0 = sptr[node], e1 = sptr[node + 1];
  int nit = (e1 - e0 + 7) >> 3;
  for (int it = 0; it < nit; ++it) {
    int e = e0 + it * 8 + slot;
    bool valid = e < e1;
    int dd = sdst[valid ? e : e1 - 1];
    const unsigned* xp = x8 + dd * 64 + w * 8;
    uint4 a = *(const uint4*)xp;
    uint4 b = *(const uint4*)(xp + 4);
    float vm = valid ? 1.f : 0.f;
    unsigned wd[8] = {a.x, a.y, a.z, a.w, b.x, b.y, b.z, b.w};
#pragma unroll
    for (int k = 0; k < 8; ++k) {
      float4 f = dec_fp8x4(wd[k]);
      sum[k*4+0] = fmaf(vm, f.x, sum[k*4+0]);
      sum[k*4+1] = fmaf(vm, f.y, sum[k*4+1]);
      sum[k*4+2] = fmaf(vm, f.z, sum[k*4+2]);
      sum[k*4+3] = fmaf(vm, f.w, sum[k*4+3]);
    }
  }
#pragma unroll
  for (int i = 0; i < 32; ++i) {
    sum[i] += __shfl_xor(sum[i], 8);
    sum[i] += __shfl_xor(sum[i], 16);
    sum[i] += __shfl_xor(sum[i], 32);
  }
  float rcnt = 1.0f / fmaxf((float)(e1 - e0), 1.0f);
  const float4* xp4 = (const float4*)(x + (size_t)node * 256 + w * 32);
  float ss = 0.f;
#pragma unroll
  for (int k = 0; k < 8; ++k) {
    float4 xm = xp4[k];
    float d0 = xm.x - sum[k*4+0] * rcnt;
    float d1 = xm.y - sum[k*4+1] * rcnt;
    float d2 = xm.z - sum[k*4+2] * rcnt;
    float d3 = xm.w - sum[k*4+3] * rcnt;
    ss += d0*d0 + d1*d1 + d2*d2 + d3*d3;
  }
  ss += __shfl_xor(ss, 1);  ss += __shfl_xor(ss, 2);  ss += __shfl_xor(ss, 4);
  ss += __shfl_xor(ss, 8);  ss += __shfl_xor(ss, 16); ss += __shfl_xor(ss, 32);
  if (lane == 0) fvar[node] = sqrtf(ss * 0.125f);
}

// ===================== global maxes: single block, LDS tree =====================
__global__ __launch_bounds__(1024) void maxred_kernel(
    const int* __restrict__ sptr, const int* __restrict__ sp_i,
    const float* __restrict__ fvar, float* __restrict__ maxf, int N)
{
  __shared__ float l0[1024], l1[1024], l2[1024];
  int tid = threadIdx.x;
  float m0 = 0.f, m1 = 0.f, m2 = 0.f;
  for (int i = tid; i < N; i += 1024) {
    m0 = fmaxf(m0, (float)(sptr[i + 1] - sptr[i]));
    m1 = fmaxf(m1, (float)(sp_i[i] - 1));
    m2 = fmaxf(m2, fvar[i]);
  }
  l0[tid] = m0; l1[tid] = m1; l2[tid] = m2;
  __syncthreads();
  for (int off = 512; off > 0; off >>= 1) {
    if (tid < off) {
      l0[tid] = fmaxf(l0[tid], l0[tid + off]);
      l1[tid] = fmaxf(l1[tid], l1[tid + off]);
      l2[tid] = fmaxf(l2[tid], l2[tid + off]);
    }
    __syncthreads();
  }
  if (tid == 0) { maxf[0] = l0[0]; maxf[1] = l1[0]; maxf[2] = l2[0]; }
}

// ===================== fused density GEMM: dfh = relu(dens@Wd1^T+bd1) @ Wd2^T + bd2 ==========
// A computed on the fly into swizzled LDS; B = wd2h staged via gld_lds (pre-swizzled source).
__global__ __launch_bounds__(256) void gemm_wd2(
    const int* __restrict__ sptr, const int* __restrict__ sp_i, const float* __restrict__ fvar,
    const float* __restrict__ maxf, const float* __restrict__ Wd1, const float* __restrict__ bd1,
    const f16* __restrict__ B, const float* __restrict__ bd2,
    f16* __restrict__ dfh, int N, int Mp)
{
  __shared__ f16 As[128 * 64];
  __shared__ f16 Bs[128 * 64];
  const int s = blockIdx.z;
  const int tid = threadIdx.x;
  const int lane = tid & 63;
  const int w = tid >> 6;
  const int wr = (w >> 1) * 64, wc = (w & 1) * 64;
  const int srow = tid >> 3;
  const int c = tid & 7;
  const int scolB = ((c ^ (srow & 7))) * 8;
  const f16* Bb = B + (size_t)s * 32768 + (size_t)(blockIdx.y * 128 + srow) * 128 + scolB;
  char* Bsl = (char*)Bs + tid * 16;
  const float dm = maxf[0] + 1e-8f, sm = maxf[1] + 1e-8f, fm = maxf[2] + 1e-8f;

  f32x4 acc[4][4] = {};

  for (int kt = 0; kt < 128; kt += 64) {
    __syncthreads();
#pragma unroll
    for (int i = 0; i < 4; ++i)
      gld_lds16(Bb + (size_t)i * 32 * 128 + kt, Bsl + i * 4096);
    // A-tile computed in-place (swizzled position c holds k-chunk c^(r&7))
#pragma unroll
    for (int i = 0; i < 4; ++i) {
      int r = srow + i * 32;
      int node = blockIdx.x * 128 + r;
      float d0 = 0.f, d1 = 0.f, d2 = 0.f;
      if (node < N) {
        d0 = (float)(sptr[node + 1] - sptr[node]) / dm;
        d1 = (float)(sp_i[node] - 1) / sm;
        d2 = fvar[node] / fm;
      }
      int kc8 = c ^ (r & 7);
      const float* w1 = Wd1 + s * 384 + (kt + kc8 * 8) * 3;
      const float* b1 = bd1 + s * 128 + kt + kc8 * 8;
      f16x8 hv;
#pragma unroll
      for (int j = 0; j < 8; ++j) {
        float h = fmaf(w1[j*3], d0, fmaf(w1[j*3+1], d1, fmaf(w1[j*3+2], d2, b1[j])));
        hv[j] = (f16)fmaxf(h, 0.f);
      }
      *(f16x8*)&As[r * 64 + c * 8] = hv;
    }
    __syncthreads();
#pragma unroll
    for (int kq = 0; kq < 2; ++kq) {
      const int krd = kq * 32 + (lane >> 4) * 8;
      const int kc = krd >> 3;
      f16x8 af[4], bfr[4];
#pragma unroll
      for (int t = 0; t < 4; ++t) {
        const int ra = wr + t * 16 + (lane & 15);
        const int rb = wc + t * 16 + (lane & 15);
        af[t]  = *(const f16x8*)&As[ra * 64 + (kc ^ (ra & 7)) * 8];
        bfr[t] = *(const f16x8*)&Bs[rb * 64 + (kc ^ (rb & 7)) * 8];
      }
#pragma unroll
      for (int mi = 0; mi < 4; ++mi)
#pragma unroll
        for (int ni = 0; ni < 4; ++ni)
          acc[mi][ni] = __builtin_amdgcn_mfma_f32_16x16x32_f16(af[mi], bfr[ni], acc[mi][ni], 0, 0, 0);
    }
  }

  const int r0 = (lane >> 4) << 2;
  const int c0 = lane & 15;
#pragma unroll
  for (int mi = 0; mi < 4; ++mi) {
#pragma unroll
    for (int ni = 0; ni < 4; ++ni) {
      int col = blockIdx.y * 128 + wc + ni * 16 + c0;
      float bv = bd2[s * 256 + col];
#pragma unroll
      for (int r = 0; r < 4; ++r) {
        int row = blockIdx.x * 128 + wr + mi * 16 + r0 + r;
        dfh[(size_t)s * Mp * 256 + (size_t)row * 256 + col] = (f16)(acc[mi][ni][r] + bv);
      }
    }
  }
}

// ===================== fp16 MFMA GEMM, scale-batched, XOR-swizzled LDS, split fp8 output =====
__global__ __launch_bounds__(256) void gemm_bt_f16(
    const f16* __restrict__ A, int lda, long sA,
    const f16* __restrict__ B, int ldb, long sB,
    const float* __restrict__ bias, int sBias,
    void* __restrict__ Cv, int ldc, long sC, int K, int Mstore, int outMode,
    unsigned char* __restrict__ Cv2, int ldc2, long sC2, int ysplit)
{
  __shared__ f16 As[128 * 64];
  __shared__ f16 Bs[128 * 64];
  const int s = blockIdx.z;
  const int tid = threadIdx.x;
  const int lane = tid & 63;
  const int w = tid >> 6;
  const int wr = (w >> 1) * 64, wc = (w & 1) * 64;
  const int srow = tid >> 3;
  const int scol = (((tid & 7) ^ (srow & 7))) * 8;   // pre-swizzled source (rule #21)
  const f16* Ab = A + (size_t)s * sA + (size_t)(blockIdx.x * 128 + srow) * lda + scol;
  const f16* Bb = B + (size_t)s * sB + (size_t)(blockIdx.y * 128 + srow) * ldb + scol;
  char* Asl = (char*)As + tid * 16;
  char* Bsl = (char*)Bs + tid * 16;

  f32x4 acc[4][4] = {};

  for (int kt = 0; kt < K; kt += 64) {
    __syncthreads();
#pragma unroll
    for (int i = 0; i < 4; ++i) {
      gld_lds16(Ab + (size_t)i * 32 * lda + kt, Asl + i * 4096);
      gld_lds16(Bb + (size_t)i * 32 * ldb + kt, Bsl + i * 4096);
    }
    __syncthreads();
#pragma unroll
    for (int kq = 0; kq < 2; ++kq) {
      const int krd = kq * 32 + (lane >> 4) * 8;
      const int kc = krd >> 3;
      f16x8 af[4], bfr[4];
#pragma unroll
      for (int t = 0; t < 4; ++t) {
        const int ra = wr + t * 16 + (lane & 15);
        const int rb = wc + t * 16 + (lane & 15);
        af[t]  = *(const f16x8*)&As[ra * 64 + (kc ^ (ra & 7)) * 8];
        bfr[t] = *(const f16x8*)&Bs[rb * 64 + (kc ^ (rb & 7)) * 8];
      }
#pragma unroll
      for (int mi = 0; mi < 4; ++mi)
#pragma unroll
        for (int ni = 0; ni < 4; ++ni)
          acc[mi][ni] = __builtin_amdgcn_mfma_f32_16x16x32_f16(af[mi], bfr[ni], acc[mi][ni], 0, 0, 0);
    }
  }

  const int r0 = (lane >> 4) << 2;
  const int c0 = lane & 15;
  const bool f8p = ((int)blockIdx.y >= ysplit);
  const int cbase = f8p ? ((int)blockIdx.y - ysplit) * 128 : (int)blockIdx.y * 128;
#pragma unroll
  for (int mi = 0; mi < 4; ++mi) {
#pragma unroll
    for (int ni = 0; ni < 4; ++ni) {
      int col = cbase + wc + ni * 16 + c0;
      float bv = (!f8p && bias) ? bias[s * sBias + col] : 0.0f;
#pragma unroll
      for (int r = 0; r < 4; ++r) {
        int row = blockIdx.x * 128 + wr + mi * 16 + r0 + r;
        if (row < Mstore) {
          float v = acc[mi][ni][r] + bv;
          if (f8p) {
            unsigned pk = __builtin_amdgcn_cvt_pk_fp8_f32(v, v, 0u, false);
            Cv2[(size_t)s * sC2 + (size_t)row * ldc2 + col] = (unsigned char)(pk & 0xffu);
          } else if (outMode == 1) {
            ((f16*)Cv)[(size_t)s * sC + (size_t)row * ldc + col] = (f16)v;
          } else {
            ((float*)Cv)[(size_t)s * sC + (size_t)row * ldc + col] = v;
          }
        }
      }
    }
  }
}

// ===================== normalize df rows -> dfn (fp8), batched over scales =====================
__global__ __launch_bounds__(256) void norm_kernel(const f16* __restrict__ dfh,
                                                   unsigned* __restrict__ drec8, int N, int Mp)
{
  int wv = threadIdx.x >> 6, lane = threadIdx.x & 63;
  int node = blockIdx.x * 4 + wv;
  if (node >= N) return;
  int s = blockIdx.y;
  float4 d = ld4h(dfh + (size_t)s * Mp * 256 + (size_t)node * 256 + lane * 4);
  float ss = d.x * d.x + d.y * d.y + d.z * d.z + d.w * d.w;
  ss += __shfl_xor(ss, 1);  ss += __shfl_xor(ss, 2);  ss += __shfl_xor(ss, 4);
  ss += __shfl_xor(ss, 8);  ss += __shfl_xor(ss, 16); ss += __shfl_xor(ss, 32);
  float rn = 1.0f / fmaxf(sqrtf(ss), 1e-8f);
  drec8[(size_t)s * Mp * 64 + node * 64 + lane] = enc_fp8x4(d.x * rn, d.y * rn, d.z * rn, d.w * rn);
}

// ===================== edge attention: wave/node, slot(4) x sub(16), erec 1-ahead prefetch =====
// nrec row (per node, f16, 512): [0:256)=q [256:512)=v ; krec8/drec8: fp8 (64 u32 words per node)
// aggc: concat layout, row stride 768, scale s cols [s*256, s*256+256)
__global__ __launch_bounds__(256) void edge_attn(
    const f16* __restrict__ nrec0, const unsigned* __restrict__ krec0,
    const unsigned* __restrict__ drec0, const int2* __restrict__ erec,
    const int* __restrict__ dptr, const int* __restrict__ perm,
    const float* __restrict__ enc_tab, const float* __restrict__ temp,
    f16* __restrict__ aggc, int N, int Mp)
{
  int wv = threadIdx.x >> 6, lane = threadIdx.x & 63;
  int node = blockIdx.x * 4 + wv;
  if (node >= N) return;
  node = perm[node];   // degree-descending schedule
  const int s = blockIdx.y;
  const int sshift = 7 * s;
  const f16* nrec = nrec0 + (size_t)s * Mp * 512;
  const unsigned* krec8 = krec0 + (size_t)s * Mp * 64;
  const unsigned* drec8 = drec0 + (size_t)s * Mp * 64;
  const float* enc_s = enc_tab + s * 1600;

  const int slot = lane >> 4;   // edge slot 0..3
  const int sub  = lane & 15;   // head(3b)<<1 | half
  const int hd   = sub >> 1;
  const int half = sub & 1;
  const int doff = hd * 8 + half * 4;
  const int voff = hd * 32 + half * 16;

  float qf[16];
  {
    const f16* qp = nrec + (size_t)node * 512 + voff;
    f16x8 a = *(const f16x8*)qp;
    f16x8 b = *(const f16x8*)(qp + 8);
#pragma unroll
    for (int j = 0; j < 8; ++j) { qf[j] = (float)a[j]; qf[8 + j] = (float)b[j]; }
  }
  uint4 diw = *(const uint4*)(drec8 + node * 64 + doff);
  const float inv_th = 0.17677669529663687f / temp[s * 8 + hd];

  float m = -1e30f, z = 0.f;
  float acc[16];
#pragma unroll
  for (int i = 0; i < 16; ++i) acc[i] = 0.f;

  int e0 = dptr[node], e1 = dptr[node + 1];
  int nit = (e1 - e0 + 3) >> 2;
  if (nit > 0) {
    int ce = e0 + slot; if (ce >= e1) ce = e1 - 1;
    int2 recA = erec[ce];
    for (int it = 0; it < nit; ++it) {
      // prefetch next iteration's record (flies during current compute)
      int en = e0 + (it + 1) * 4 + slot; en = (en < e1) ? en : e1 - 1;
      int2 recN = erec[en];

      int e = e0 + it * 4 + slot;
      bool valid = e < e1;
      int src = recA.x;
      unsigned pb = (unsigned)recA.y;
      uint4 kwv = *(const uint4*)(krec8 + src * 64 + doff);
      uint4 dwv = *(const uint4*)(drec8 + src * 64 + doff);
      const f16* vp = nrec + (size_t)src * 512 + 256 + voff;
      f16x8 vs0 = *(const f16x8*)vp;
      f16x8 vs1 = *(const f16x8*)(vp + 8);
      float enc = enc_s[((pb >> sshift) & 127u) * 16 + (pb >> 21)];

      unsigned kw[4] = {kwv.x, kwv.y, kwv.z, kwv.w};
      unsigned dw[4] = {dwv.x, dwv.y, dwv.z, dwv.w};
      unsigned di[4] = {diw.x, diw.y, diw.z, diw.w};
      float qk0 = 0.f, qk1 = 0.f, ds0 = 0.f, ds1 = 0.f;
#pragma unroll
      for (int w = 0; w < 4; ++w) {
        float4 kf = dec_fp8x4(kw[w]);
        qk0 = fmaf(qf[w*4+0], kf.x, qk0);
        qk1 = fmaf(qf[w*4+1], kf.y, qk1);
        qk0 = fmaf(qf[w*4+2], kf.z, qk0);
        qk1 = fmaf(qf[w*4+3], kf.w, qk1);
        float4 df = dec_fp8x4(dw[w]);
        float4 dd = dec_fp8x4(di[w]);
        ds0 = fmaf(dd.x, df.x, ds0);
        ds1 = fmaf(dd.y, df.y, ds1);
        ds0 = fmaf(dd.z, df.z, ds0);
        ds1 = fmaf(dd.w, df.w, ds1);
      }
      float qk = qk0 + qk1;
      float ds = ds0 + ds1;
      qk += __shfl_xor(qk, 1);
      ds += __shfl_xor(ds, 1); ds += __shfl_xor(ds, 2);
      ds += __shfl_xor(ds, 4); ds += __shfl_xor(ds, 8);

      float sc = (qk * inv_th + enc) * (1.0f + 0.5f * ds);
      sc = valid ? sc : -1e30f;
      if (__any(sc > m + 8.0f)) {
        float mn = fmaxf(m, sc);
        float rs = __expf(m - mn);
        z *= rs;
#pragma unroll
        for (int i = 0; i < 16; ++i) acc[i] *= rs;
        m = mn;
      }
      float p = __expf(sc - m) * (valid ? 1.0f : 0.0f);
      z += p;
#pragma unroll
      for (int j = 0; j < 8; ++j) acc[j]     = fmaf(p, (float)vs0[j], acc[j]);
#pragma unroll
      for (int j = 0; j < 8; ++j) acc[8 + j] = fmaf(p, (float)vs1[j], acc[8 + j]);

      recA = recN;
    }
  }

  // merge the 4 slots (lane bits 4..5), same sub
  float M = m;
  M = fmaxf(M, __shfl_xor(M, 16));
  M = fmaxf(M, __shfl_xor(M, 32));
  float f = __expf(m - M);
  z *= f;
  z += __shfl_xor(z, 16); z += __shfl_xor(z, 32);
#pragma unroll
  for (int i = 0; i < 16; ++i) {
    float a = acc[i] * f;
    a += __shfl_xor(a, 16); a += __shfl_xor(a, 32);
    acc[i] = a;
  }
  float rz = 1.0f / (z + 1e-16f);
  if (slot == 0) {
    f16* op = aggc + (size_t)node * 768 + s * 256 + voff;
    f16x8 o0, o1;
#pragma unroll
    for (int j = 0; j < 8; ++j) { o0[j] = (f16)(acc[j] * rz); o1[j] = (f16)(acc[8 + j] * rz); }
    *(f16x8*)op = o0;
    *(f16x8*)(op + 8) = o1;
  }
}

// ===================== host launcher =====================
extern "C" void kernel_launch(void* const* d_in, const int* in_sizes, int n_in,
                              void* d_out, int out_size, void* d_ws, size_t ws_size,
                              hipStream_t stream)
{
  const float* x      = (const float*)d_in[0];
  const float* coords = (const float*)d_in[1];
  const int*   eidx   = (const int*)  d_in[2];
  const float* Wq   = (const float*)d_in[3];
  const float* Wk   = (const float*)d_in[4];
  const float* Wv   = (const float*)d_in[5];
  const float* Wo   = (const float*)d_in[6];
  const float* bo   = (const float*)d_in[7];
  const float* temp = (const float*)d_in[8];
  const float* dist_emb = (const float*)d_in[9];
  const float* dir_emb  = (const float*)d_in[10];
  const float* Wsp1 = (const float*)d_in[11];
  const float* bsp1 = (const float*)d_in[12];
  const float* Wsp2 = (const float*)d_in[13];
  const float* bsp2 = (const float*)d_in[14];
  const float* Wd1  = (const float*)d_in[15];
  const float* bd1  = (const float*)d_in[16];
  const float* Wd2  = (const float*)d_in[17];
  const float* bd2  = (const float*)d_in[18];
  const float* Wf   = (const float*)d_in[19];
  const float* bf   = (const float*)d_in[20];
  (void)n_in; (void)out_size; (void)ws_size;

  const int N  = in_sizes[0] / 256;
  const int E  = in_sizes[2] / 2;
  const int Mp = ((N + 127) / 128) * 128;

  char* p = (char*)d_ws;
  auto alloc = [&](size_t b) -> void* {
    void* r = (void*)p;
    p += (b + 255) & ~(size_t)255;
    return r;
  };

  f16*      x_h   = (f16*)     alloc((size_t)Mp * 256 * 2);
  unsigned* x8    = (unsigned*)alloc((size_t)Mp * 256);
  f16*      nrec3 = (f16*)     alloc((size_t)3 * Mp * 512 * 2);  // q|v per node per scale
  unsigned* krec3 = (unsigned*)alloc((size_t)3 * Mp * 256);
  unsigned* drec3 = (unsigned*)alloc((size_t)3 * Mp * 256);
  f16*      dfh3  = (f16*)     alloc((size_t)3 * Mp * 256 * 2);
  f16*      aggc  = (f16*)     alloc((size_t)Mp * 768 * 2);      // concat agg, row stride 768
  f16*      wqvk  = (f16*)     alloc((size_t)3 * 768 * 256 * 2);
  f16*      wfo   = (f16*)     alloc((size_t)256 * 768 * 2);
  float*    bias_f = (float*)  alloc(256 * 4);
  f16*      wd2h  = (f16*)     alloc((size_t)3 * 256 * 128 * 2);
  float*    enc_tab = (float*) alloc((size_t)3 * 1600 * 4);
  int*    dptr = (int*)   alloc((size_t)(N + 1) * 4);
  int*    sptr = (int*)   alloc((size_t)(N + 1) * 4);
  int*    cptr = (int*)   alloc((size_t)401 * 4);
  int*    perm = (int*)   alloc((size_t)N * 4);
  int2*   erec = (int2*)  alloc((size_t)E * 8);
  int*    sdst = (int*)   alloc((size_t)E * 4);
  float2* scoord = (float2*)alloc((size_t)N * 8);
  float*  fvar = (float*) alloc((size_t)N * 4);
  int*    sp_i = (int*)   alloc((size_t)N * 4);
  float*  maxf = (float*) alloc(4 * 4);
  // ---- zeroed-every-call block ----
  char* z0 = p;
  int* deg_i   = (int*)alloc((size_t)N * 4);
  int* indeg_i = (int*)alloc((size_t)N * 4);
  int* fill_d  = (int*)alloc((size_t)N * 4);
  int* fill_s  = (int*)alloc((size_t)N * 4);
  int* cellcnt = (int*)alloc(400 * 4);
  int* fill_c  = (int*)alloc(400 * 4);
  size_t zbytes = (size_t)(p - z0);
  hipMemsetAsync(z0, 0, zbytes, stream);

  const int hb = (E + 255) / 256;
  // 1. prep: cast + enc tables + histograms + Wfo + fused bias (one dispatch)
  prep_kernel<<<2067 + hb + 768 + 1, 256, 0, stream>>>(
      x, Wq, Wk, Wv, Wd2, x_h, x8, wqvk, wd2h,
      dist_emb, dir_emb, Wsp1, bsp1, Wsp2, bsp2, enc_tab,
      eidx, coords, deg_i, indeg_i, cellcnt,
      Wf, Wo, bo, bf, wfo, bias_f, E, N, hb);
  // 2. scans + degree-desc perm (4 independent blocks)
  scan_kernel<<<4, 1024, 0, stream>>>(indeg_i, deg_i, cellcnt, dptr, sptr, cptr, perm, N);
  // 3. CSR scatter + edge bins + cell scatter
  scatter_kernel<<<(E + 255) / 256, 256, 0, stream>>>(eidx, coords, dptr, sptr, cptr,
                                                      fill_d, fill_s, fill_c, erec, sdst, scoord, E, N);
  // 4. node stats: spatial density + fvar
  node_stats_kernel<<<(N + 3) / 4, 256, 0, stream>>>(coords, scoord, cptr, x, x8,
                                                     sptr, sdst, sp_i, fvar, N);
  // 5. maxes
  maxred_kernel<<<1, 1024, 0, stream>>>(sptr, sp_i, fvar, maxf, N);

  const int mtiles = Mp / 128;
  // 6. fused density GEMM (h computed on the fly), all scales
  gemm_wd2<<<dim3(mtiles, 2, 3), 256, 0, stream>>>(sptr, sp_i, fvar, maxf, Wd1, bd1,
                                                   wd2h, bd2, dfh3, N, Mp);
  // 7. normalize -> fp8 dfn, all scales
  norm_kernel<<<dim3((N + 3) / 4, 3), 256, 0, stream>>>(dfh3, drec3, N, Mp);
  // 8. q,v (f16) and k (fp8) in one split-output GEMM, all scales
  gemm_bt_f16<<<dim3(mtiles, 6, 3), 256, 0, stream>>>(x_h, 256, 0,
                                                      wqvk, 256, 196608, nullptr, 0,
                                                      nrec3, 512, (long)Mp * 512, 256, Mp, 1,
                                                      (unsigned char*)krec3, 256, (long)Mp * 256, 4);
  // 9. edge attention + scatter softmax + aggregate (slot4 x sub16, prefetched)
  edge_attn<<<dim3((N + 3) / 4, 3), 256, 0, stream>>>(nrec3, krec3, drec3, erec, dptr, perm,
                                                      enc_tab, temp, aggc, N, Mp);
  // 10. fused (Wo then Wf) GEMM: out = aggc @ Wfo^T + bias_f  -> d_out f32
  gemm_bt_f16<<<dim3(mtiles, 2, 1), 256, 0, stream>>>(aggc, 768, 0,
                                                      wfo, 768, 0, bias_f, 0,
                                                      d_out, 256, 0, 768, N, 0,
                                                      nullptr, 0, 0, 99);
}

// Round 13
// 332.226 us; speedup vs baseline: 1.4317x; 1.0122x over previous
//
#include <hip/hip_runtime.h>

typedef _Float16 f16;
typedef _Float16 f16x4 __attribute__((ext_vector_type(4)));
typedef _Float16 f16x8 __attribute__((ext_vector_type(8)));
typedef float    f32x4 __attribute__((ext_vector_type(4)));
typedef float    fv2   __attribute__((ext_vector_type(2)));

__device__ __forceinline__ float4 ld4h(const f16* p) {
  f16x4 t = *(const f16x4*)p;
  return make_float4((float)t[0], (float)t[1], (float)t[2], (float)t[3]);
}

__device__ __forceinline__ float4 dec_fp8x4(unsigned u) {
  fv2 lo = __builtin_amdgcn_cvt_pk_f32_fp8(u, false);
  fv2 hi = __builtin_amdgcn_cvt_pk_f32_fp8(u, true);
  return make_float4(lo[0], lo[1], hi[0], hi[1]);
}

__device__ __forceinline__ unsigned enc_fp8x4(float a, float b, float c, float d) {
  unsigned v = 0;
  v = __builtin_amdgcn_cvt_pk_fp8_f32(a, b, v, false);
  v = __builtin_amdgcn_cvt_pk_fp8_f32(c, d, v, true);
  return v;
}

__device__ __forceinline__ void gld_lds16(const void* g, void* l) {
  __builtin_amdgcn_global_load_lds(
      (const __attribute__((address_space(1))) unsigned*)g,
      (__attribute__((address_space(3))) unsigned*)l, 16, 0, 0);
}

__device__ __forceinline__ int cell_of(const float* coords, int i) {
  int cx = (int)(coords[2 * i] * 0.02f);
  int cy = (int)(coords[2 * i + 1] * 0.02f);
  cx = cx < 0 ? 0 : (cx > 19 ? 19 : cx);
  cy = cy < 0 ? 0 : (cy > 19 ? 19 : cy);
  return cy * 20 + cx;
}

// ===================== shared MFMA GEMM core (XOR-swizzled LDS, split fp8 output) =====================
__device__ __forceinline__ void gemm_core(
    f16* As, f16* Bs, int bx, int by, int s,
    const f16* __restrict__ A, int lda, long sA,
    const f16* __restrict__ B, int ldb, long sB,
    const float* __restrict__ bias, int sBias,
    void* __restrict__ Cv, int ldc, long sC, int K, int Mstore, int outMode,
    unsigned char* __restrict__ Cv2, int ldc2, long sC2, int ysplit)
{
  const int tid = threadIdx.x;
  const int lane = tid & 63;
  const int w = tid >> 6;
  const int wr = (w >> 1) * 64, wc = (w & 1) * 64;
  const int srow = tid >> 3;
  const int scol = (((tid & 7) ^ (srow & 7))) * 8;   // pre-swizzled source (rule #21)
  const f16* Ab = A + (size_t)s * sA + (size_t)(bx * 128 + srow) * lda + scol;
  const f16* Bb = B + (size_t)s * sB + (size_t)(by * 128 + srow) * ldb + scol;
  char* Asl = (char*)As + tid * 16;
  char* Bsl = (char*)Bs + tid * 16;

  f32x4 acc[4][4] = {};

  for (int kt = 0; kt < K; kt += 64) {
    __syncthreads();
#pragma unroll
    for (int i = 0; i < 4; ++i) {
      gld_lds16(Ab + (size_t)i * 32 * lda + kt, Asl + i * 4096);
      gld_lds16(Bb + (size_t)i * 32 * ldb + kt, Bsl + i * 4096);
    }
    __syncthreads();
#pragma unroll
    for (int kq = 0; kq < 2; ++kq) {
      const int krd = kq * 32 + (lane >> 4) * 8;
      const int kc = krd >> 3;
      f16x8 af[4], bfr[4];
#pragma unroll
      for (int t = 0; t < 4; ++t) {
        const int ra = wr + t * 16 + (lane & 15);
        const int rb = wc + t * 16 + (lane & 15);
        af[t]  = *(const f16x8*)&As[ra * 64 + (kc ^ (ra & 7)) * 8];
        bfr[t] = *(const f16x8*)&Bs[rb * 64 + (kc ^ (rb & 7)) * 8];
      }
#pragma unroll
      for (int mi = 0; mi < 4; ++mi)
#pragma unroll
        for (int ni = 0; ni < 4; ++ni)
          acc[mi][ni] = __builtin_amdgcn_mfma_f32_16x16x32_f16(af[mi], bfr[ni], acc[mi][ni], 0, 0, 0);
    }
  }

  const int r0 = (lane >> 4) << 2;
  const int c0 = lane & 15;
  const bool f8p = (by >= ysplit);
  const int cbase = f8p ? (by - ysplit) * 128 : by * 128;
#pragma unroll
  for (int mi = 0; mi < 4; ++mi) {
#pragma unroll
    for (int ni = 0; ni < 4; ++ni) {
      int col = cbase + wc + ni * 16 + c0;
      float bv = (!f8p && bias) ? bias[s * sBias + col] : 0.0f;
#pragma unroll
      for (int r = 0; r < 4; ++r) {
        int row = bx * 128 + wr + mi * 16 + r0 + r;
        if (row < Mstore) {
          float v = acc[mi][ni][r] + bv;
          if (f8p) {
            unsigned pk = __builtin_amdgcn_cvt_pk_fp8_f32(v, v, 0u, false);
            Cv2[(size_t)s * sC2 + (size_t)row * ldc2 + col] = (unsigned char)(pk & 0xffu);
          } else if (outMode == 1) {
            ((f16*)Cv)[(size_t)s * sC + (size_t)row * ldc + col] = (f16)v;
          } else {
            ((float*)Cv)[(size_t)s * sC + (size_t)row * ldc + col] = v;
          }
        }
      }
    }
  }
}

// ===== prep: cast | enc tables | hist | wfo (tiled) | biasf (block-range partitioned) =====
// wqvk layout per scale: rows [0:256)=q, [256:512)=v, [512:768)=k
__global__ __launch_bounds__(256) void prep_kernel(
    const float* __restrict__ x, const float* __restrict__ Wq, const float* __restrict__ Wk,
    const float* __restrict__ Wv, const float* __restrict__ Wd2,
    f16* __restrict__ x_h, unsigned* __restrict__ x8, f16* __restrict__ wqvk,
    f16* __restrict__ wd2h,
    const float* __restrict__ dist_emb, const float* __restrict__ dir_emb,
    const float* __restrict__ Wsp1, const float* __restrict__ bsp1,
    const float* __restrict__ Wsp2, const float* __restrict__ bsp2,
    float* __restrict__ enc_tab,
    const int* __restrict__ eidx, const float* __restrict__ coords,
    int* deg_i, int* indeg_i, int* cellcnt,
    const float* __restrict__ Wf, const float* __restrict__ Wo,
    const float* __restrict__ bo, const float* __restrict__ bf,
    f16* __restrict__ wfo, float* __restrict__ bias_f,
    int E, int N, int hb)
{
  const int b = blockIdx.x;
  if (b < 2048) {
    const int n0 = N * 64;
    const int total = n0 + 147456 + 24576;
    for (int i = b * 256 + threadIdx.x; i < total; i += 2048 * 256) {
      int k = i;
      if (k < n0) {
        float4 v = ((const float4*)x)[k];
        f16x4 o; o[0] = (f16)v.x; o[1] = (f16)v.y; o[2] = (f16)v.z; o[3] = (f16)v.w;
        ((f16x4*)x_h)[k] = o;
        x8[k] = enc_fp8x4(v.x, v.y, v.z, v.w);
        continue;
      }
      const float4* sp; f16x4* dp;
      k -= n0;
      if (k < 147456) {
        int s = k / 49152, r = k % 49152, m = r / 16384, off = r % 16384;
        const float* w = (m == 0) ? Wq : (m == 1) ? Wk : Wv;
        int dblk = (m == 0) ? 0 : (m == 1) ? 32768 : 16384;
        sp = (const float4*)(w + s * 65536) + off;
        dp = (f16x4*)wqvk + s * 49152 + dblk + off;
      } else {
        k -= 147456;
        sp = (const float4*)Wd2 + k; dp = (f16x4*)wd2h + k;
      }
      float4 v = *sp;
      f16x4 o; o[0] = (f16)v.x; o[1] = (f16)v.y; o[2] = (f16)v.z; o[3] = (f16)v.w;
      *dp = o;
    }
  } else if (b < 2067) {
    int id = (b - 2048) * 256 + threadIdx.x;
    if (id >= 3 * 1600) return;
    int s = id / 1600, c = id % 1600, db = c >> 4, ab = c & 15;
    const float* de = dist_emb + (size_t)(s * 100 + db) * 16;
    const float* ae = dir_emb + (size_t)(s * 16 + ab) * 16;
    const float* w1 = Wsp1 + s * 1024;
    const float* b1 = bsp1 + s * 32;
    const float* w2 = Wsp2 + s * 32;
    float enc = bsp2[s];
    for (int j = 0; j < 32; ++j) {
      float a = b1[j];
      const float* wr = w1 + j * 32;
#pragma unroll
      for (int i = 0; i < 16; ++i) a += de[i] * wr[i];
#pragma unroll
      for (int i = 0; i < 16; ++i) a += ae[i] * wr[16 + i];
      enc += fmaxf(a, 0.0f) * w2[j];
    }
    enc_tab[id] = enc;
  } else if (b < 2067 + hb) {
    int e = (b - 2067) * 256 + threadIdx.x;
    if (e < E) {
      atomicAdd(&deg_i[eidx[e]], 1);
      atomicAdd(&indeg_i[eidx[E + e]], 1);
    }
    if (e < N) atomicAdd(&cellcnt[cell_of(coords, e)], 1);
  } else if (b < 2067 + hb + 96) {
    // Wfo = Wf_s @ Wo_s, tiled: 8 output rows per block, LDS-broadcast Wf
    __shared__ float wf8[8][256];
    int idx = b - (2067 + hb);
    int s = idx / 32;
    int og = (idx % 32) * 8;
    int j = threadIdx.x;
#pragma unroll
    for (int oo = 0; oo < 8; ++oo) wf8[oo][j] = Wf[(og + oo) * 768 + s * 256 + j];
    __syncthreads();
    const float* wo = Wo + (size_t)s * 65536 + j;
    float acc[8] = {0.f, 0.f, 0.f, 0.f, 0.f, 0.f, 0.f, 0.f};
    for (int m = 0; m < 256; ++m) {
      float val = wo[(size_t)m * 256];
#pragma unroll
      for (int oo = 0; oo < 8; ++oo) acc[oo] = fmaf(wf8[oo][m], val, acc[oo]);
    }
#pragma unroll
    for (int oo = 0; oo < 8; ++oo)
      wfo[(size_t)(og + oo) * 768 + s * 256 + j] = (f16)acc[oo];
  } else {
    // fused bias
    int j = threadIdx.x;
    float acc = bf[j];
    const float* wr = Wf + (size_t)j * 768;
    for (int t = 0; t < 768; ++t) acc = fmaf(bo[t], wr[t], acc);
    bias_f[j] = acc;
  }
}

// ===================== scans (passes 0-2) + degree-desc perm (pass 3) =====================
__global__ __launch_bounds__(1024) void scan_kernel(const int* __restrict__ indeg,
                                                    const int* __restrict__ deg,
                                                    const int* __restrict__ cellcnt,
                                                    int* dptr, int* sptr, int* cptr,
                                                    int* __restrict__ perm, int N)
{
  __shared__ int lds[1024];
  __shared__ int cnt[256], scn2[256], fill[256];
  const int tid = threadIdx.x;
  const int pass = blockIdx.x;
  if (pass == 3) {
    if (tid < 256) { cnt[tid] = 0; fill[tid] = 0; }
    __syncthreads();
    for (int n = tid; n < N; n += 1024) {
      int d = indeg[n];
      int key = 255 - (d > 255 ? 255 : d);
      atomicAdd(&cnt[key], 1);
    }
    __syncthreads();
    if (tid < 256) scn2[tid] = cnt[tid];
    __syncthreads();
    for (int off = 1; off < 256; off <<= 1) {
      int v = 0;
      if (tid < 256 && tid >= off) v = scn2[tid - off];
      __syncthreads();
      if (tid < 256) scn2[tid] += v;
      __syncthreads();
    }
    for (int n = tid; n < N; n += 1024) {
      int d = indeg[n];
      int key = 255 - (d > 255 ? 255 : d);
      int pos = scn2[key] - cnt[key] + atomicAdd(&fill[key], 1);
      perm[pos] = n;
    }
    return;
  }
  const int* in = (pass == 0) ? indeg : (pass == 1) ? deg : cellcnt;
  int* out = (pass == 0) ? dptr : (pass == 1) ? sptr : cptr;
  int len = (pass == 2) ? 400 : N;
  int base = tid * 16;
  int loc[16];
  int sum = 0;
#pragma unroll
  for (int j = 0; j < 16; ++j) {
    int v = (base + j < len) ? in[base + j] : 0;
    loc[j] = sum; sum += v;
  }
  lds[tid] = sum;
  __syncthreads();
  for (int off = 1; off < 1024; off <<= 1) {
    int t = (tid >= off) ? lds[tid - off] : 0;
    __syncthreads();
    lds[tid] += t;
    __syncthreads();
  }
  int prev = tid ? lds[tid - 1] : 0;
#pragma unroll
  for (int j = 0; j < 16; ++j)
    if (base + j < len) out[base + j] = prev + loc[j];
  if (tid == 1023) out[len] = lds[1023];
}

// ===================== CSR scatter + per-edge geometry bins + cell scatter =====================
__global__ __launch_bounds__(256) void scatter_kernel(
    const int* __restrict__ eidx, const float* __restrict__ coords,
    const int* __restrict__ dptr, const int* __restrict__ sptr, const int* __restrict__ cptr,
    int* fill_d, int* fill_s, int* fill_c,
    int2* __restrict__ erec, int* __restrict__ sdst, float2* __restrict__ scoord, int E, int N)
{
  int e = blockIdx.x * 256 + threadIdx.x;
  if (e < E) {
    int s = eidx[e], d = eidx[E + e];
    float rx = coords[2 * s] - coords[2 * d];
    float ry = coords[2 * s + 1] - coords[2 * d + 1];
    float dist = sqrtf(rx * rx + ry * ry);
    float ang = atan2f(ry, rx);
    int ab = (int)((ang + 3.14159265358979323846f) / 6.28318530717958647692f * 15.0f);
    ab = ab < 0 ? 0 : (ab > 15 ? 15 : ab);
    int b0 = (int)((dist / 500.0f) * 99.0f);  b0 = b0 < 0 ? 0 : (b0 > 99 ? 99 : b0);
    int b1 = (int)((dist / 1000.0f) * 99.0f); b1 = b1 < 0 ? 0 : (b1 > 99 ? 99 : b1);
    int b2 = (int)((dist / 2000.0f) * 99.0f); b2 = b2 < 0 ? 0 : (b2 > 99 ? 99 : b2);
    unsigned pb = (unsigned)b0 | ((unsigned)b1 << 7) | ((unsigned)b2 << 14) | ((unsigned)ab << 21);
    int pd = dptr[d] + atomicAdd(&fill_d[d], 1);
    erec[pd] = make_int2(s, (int)pb);
    int ps = sptr[s] + atomicAdd(&fill_s[s], 1);
    sdst[ps] = d;
  }
  if (e < N) {
    int cid = cell_of(coords, e);
    int pc = cptr[cid] + atomicAdd(&fill_c[cid], 1);
    scoord[pc] = ((const float2*)coords)[e];
  }
}

// ===================== mid: qkv GEMM (blocks 0..qkvB) overlapped with node_stats =====================
__global__ __launch_bounds__(256) void mid_kernel(
    const f16* __restrict__ x_h, const f16* __restrict__ wqvk,
    f16* __restrict__ nrec3, unsigned char* __restrict__ krec3,
    const float* __restrict__ coords, const float2* __restrict__ scoord,
    const int* __restrict__ cptr,
    const float* __restrict__ x, const unsigned* __restrict__ x8,
    const int* __restrict__ sptr, const int* __restrict__ sdst,
    int* __restrict__ sp_i, float* __restrict__ fvar,
    int N, int Mp, int mtiles, int qkvB)
{
  __shared__ f16 As[128 * 64];
  __shared__ f16 Bs[128 * 64];
  const int b = blockIdx.x;
  if (b < qkvB) {
    int bx = b % mtiles;
    int t = b / mtiles;
    gemm_core(As, Bs, bx, t % 6, t / 6,
              x_h, 256, 0, wqvk, 256, 196608, nullptr, 0,
              nrec3, 512, (long)Mp * 512, 256, Mp, 1,
              krec3, 256, (long)Mp * 256, 4);
    return;
  }
  int wv = threadIdx.x >> 6, lane = threadIdx.x & 63;
  int node = (b - qkvB) * 4 + wv;
  if (node >= N) return;

  float cx = coords[2 * node], cy = coords[2 * node + 1];
  {
    int gx = (int)(cx * 0.02f); gx = gx < 0 ? 0 : (gx > 19 ? 19 : gx);
    int gy = (int)(cy * 0.02f); gy = gy < 0 ? 0 : (gy > 19 ? 19 : gy);
    int x0 = gx > 0 ? gx - 1 : 0, x1 = gx < 19 ? gx + 1 : 19;
    int y0 = gy > 0 ? gy - 1 : 0, y1 = gy < 19 ? gy + 1 : 19;
    int cnt = 0;
    for (int r = y0; r <= y1; ++r) {
      int j0 = cptr[r * 20 + x0], j1 = cptr[r * 20 + x1 + 1];
      for (int j = j0 + lane; j < j1; j += 64) {
        float2 c = scoord[j];
        float dx = cx - c.x, dy = cy - c.y;
        cnt += (dx * dx + dy * dy <= 2500.0f) ? 1 : 0;
      }
    }
    cnt += __shfl_xor(cnt, 1);  cnt += __shfl_xor(cnt, 2);  cnt += __shfl_xor(cnt, 4);
    cnt += __shfl_xor(cnt, 8);  cnt += __shfl_xor(cnt, 16); cnt += __shfl_xor(cnt, 32);
    if (lane == 0) sp_i[node] = cnt;
  }

  const int slot = lane >> 3, w = lane & 7;
  float sum[32];
#pragma unroll
  for (int i = 0; i < 32; ++i) sum[i] = 0.f;
  int e0 = sptr[node], e1 = sptr[node + 1];
  int nit = (e1 - e0 + 7) >> 3;
  for (int it = 0; it < nit; ++it) {
    int e = e0 + it * 8 + slot;
    bool valid = e < e1;
    int dd = sdst[valid ? e : e1 - 1];
    const unsigned* xp = x8 + dd * 64 + w * 8;
    uint4 a = *(const uint4*)xp;
    uint4 bq = *(const uint4*)(xp + 4);
    float vm = valid ? 1.f : 0.f;
    unsigned wd[8] = {a.x, a.y, a.z, a.w, bq.x, bq.y, bq.z, bq.w};
#pragma unroll
    for (int k = 0; k < 8; ++k) {
      float4 f = dec_fp8x4(wd[k]);
      sum[k*4+0] = fmaf(vm, f.x, sum[k*4+0]);
      sum[k*4+1] = fmaf(vm, f.y, sum[k*4+1]);
      sum[k*4+2] = fmaf(vm, f.z, sum[k*4+2]);
      sum[k*4+3] = fmaf(vm, f.w, sum[k*4+3]);
    }
  }
#pragma unroll
  for (int i = 0; i < 32; ++i) {
    sum[i] += __shfl_xor(sum[i], 8);
    sum[i] += __shfl_xor(sum[i], 16);
    sum[i] += __shfl_xor(sum[i], 32);
  }
  float rcnt = 1.0f / fmaxf((float)(e1 - e0), 1.0f);
  const float4* xp4 = (const float4*)(x + (size_t)node * 256 + w * 32);
  float ss = 0.f;
#pragma unroll
  for (int k = 0; k < 8; ++k) {
    float4 xm = xp4[k];
    float d0 = xm.x - sum[k*4+0] * rcnt;
    float d1 = xm.y - sum[k*4+1] * rcnt;
    float d2 = xm.z - sum[k*4+2] * rcnt;
    float d3 = xm.w - sum[k*4+3] * rcnt;
    ss += d0*d0 + d1*d1 + d2*d2 + d3*d3;
  }
  ss += __shfl_xor(ss, 1);  ss += __shfl_xor(ss, 2);  ss += __shfl_xor(ss, 4);
  ss += __shfl_xor(ss, 8);  ss += __shfl_xor(ss, 16); ss += __shfl_xor(ss, 32);
  if (lane == 0) fvar[node] = sqrtf(ss * 0.125f);
}

// ===================== global maxes: single block, LDS tree =====================
__global__ __launch_bounds__(1024) void maxred_kernel(
    const int* __restrict__ sptr, const int* __restrict__ sp_i,
    const float* __restrict__ fvar, float* __restrict__ maxf, int N)
{
  __shared__ float l0[1024], l1[1024], l2[1024];
  int tid = threadIdx.x;
  float m0 = 0.f, m1 = 0.f, m2 = 0.f;
  for (int i = tid; i < N; i += 1024) {
    m0 = fmaxf(m0, (float)(sptr[i + 1] - sptr[i]));
    m1 = fmaxf(m1, (float)(sp_i[i] - 1));
    m2 = fmaxf(m2, fvar[i]);
  }
  l0[tid] = m0; l1[tid] = m1; l2[tid] = m2;
  __syncthreads();
  for (int off = 512; off > 0; off >>= 1) {
    if (tid < off) {
      l0[tid] = fmaxf(l0[tid], l0[tid + off]);
      l1[tid] = fmaxf(l1[tid], l1[tid + off]);
      l2[tid] = fmaxf(l2[tid], l2[tid + off]);
    }
    __syncthreads();
  }
  if (tid == 0) { maxf[0] = l0[0]; maxf[1] = l1[0]; maxf[2] = l2[0]; }
}

// ===================== fused density GEMM: dfh = relu(dens@Wd1^T+bd1) @ Wd2^T + bd2 ==========
__global__ __launch_bounds__(256) void gemm_wd2(
    const int* __restrict__ sptr, const int* __restrict__ sp_i, const float* __restrict__ fvar,
    const float* __restrict__ maxf, const float* __restrict__ Wd1, const float* __restrict__ bd1,
    const f16* __restrict__ B, const float* __restrict__ bd2,
    f16* __restrict__ dfh, int N, int Mp)
{
  __shared__ f16 As[128 * 64];
  __shared__ f16 Bs[128 * 64];
  const int s = blockIdx.z;
  const int tid = threadIdx.x;
  const int lane = tid & 63;
  const int w = tid >> 6;
  const int wr = (w >> 1) * 64, wc = (w & 1) * 64;
  const int srow = tid >> 3;
  const int c = tid & 7;
  const int scolB = ((c ^ (srow & 7))) * 8;
  const f16* Bb = B + (size_t)s * 32768 + (size_t)(blockIdx.y * 128 + srow) * 128 + scolB;
  char* Bsl = (char*)Bs + tid * 16;
  const float dm = maxf[0] + 1e-8f, sm = maxf[1] + 1e-8f, fm = maxf[2] + 1e-8f;

  f32x4 acc[4][4] = {};

  for (int kt = 0; kt < 128; kt += 64) {
    __syncthreads();
#pragma unroll
    for (int i = 0; i < 4; ++i)
      gld_lds16(Bb + (size_t)i * 32 * 128 + kt, Bsl + i * 4096);
#pragma unroll
    for (int i = 0; i < 4; ++i) {
      int r = srow + i * 32;
      int node = blockIdx.x * 128 + r;
      float d0 = 0.f, d1 = 0.f, d2 = 0.f;
      if (node < N) {
        d0 = (float)(sptr[node + 1] - sptr[node]) / dm;
        d1 = (float)(sp_i[node] - 1) / sm;
        d2 = fvar[node] / fm;
      }
      int kc8 = c ^ (r & 7);
      const float* w1 = Wd1 + s * 384 + (kt + kc8 * 8) * 3;
      const float* b1 = bd1 + s * 128 + kt + kc8 * 8;
      f16x8 hv;
#pragma unroll
      for (int j = 0; j < 8; ++j) {
        float h = fmaf(w1[j*3], d0, fmaf(w1[j*3+1], d1, fmaf(w1[j*3+2], d2, b1[j])));
        hv[j] = (f16)fmaxf(h, 0.f);
      }
      *(f16x8*)&As[r * 64 + c * 8] = hv;
    }
    __syncthreads();
#pragma unroll
    for (int kq = 0; kq < 2; ++kq) {
      const int krd = kq * 32 + (lane >> 4) * 8;
      const int kc = krd >> 3;
      f16x8 af[4], bfr[4];
#pragma unroll
      for (int t = 0; t < 4; ++t) {
        const int ra = wr + t * 16 + (lane & 15);
        const int rb = wc + t * 16 + (lane & 15);
        af[t]  = *(const f16x8*)&As[ra * 64 + (kc ^ (ra & 7)) * 8];
        bfr[t] = *(const f16x8*)&Bs[rb * 64 + (kc ^ (rb & 7)) * 8];
      }
#pragma unroll
      for (int mi = 0; mi < 4; ++mi)
#pragma unroll
        for (int ni = 0; ni < 4; ++ni)
          acc[mi][ni] = __builtin_amdgcn_mfma_f32_16x16x32_f16(af[mi], bfr[ni], acc[mi][ni], 0, 0, 0);
    }
  }

  const int r0 = (lane >> 4) << 2;
  const int c0 = lane & 15;
#pragma unroll
  for (int mi = 0; mi < 4; ++mi) {
#pragma unroll
    for (int ni = 0; ni < 4; ++ni) {
      int col = blockIdx.y * 128 + wc + ni * 16 + c0;
      float bv = bd2[s * 256 + col];
#pragma unroll
      for (int r = 0; r < 4; ++r) {
        int row = blockIdx.x * 128 + wr + mi * 16 + r0 + r;
        dfh[(size_t)s * Mp * 256 + (size_t)row * 256 + col] = (f16)(acc[mi][ni][r] + bv);
      }
    }
  }
}

// ===================== standalone GEMM kernel (wraps gemm_core) =====================
__global__ __launch_bounds__(256) void gemm_bt_f16(
    const f16* __restrict__ A, int lda, long sA,
    const f16* __restrict__ B, int ldb, long sB,
    const float* __restrict__ bias, int sBias,
    void* __restrict__ Cv, int ldc, long sC, int K, int Mstore, int outMode,
    unsigned char* __restrict__ Cv2, int ldc2, long sC2, int ysplit)
{
  __shared__ f16 As[128 * 64];
  __shared__ f16 Bs[128 * 64];
  gemm_core(As, Bs, blockIdx.x, blockIdx.y, blockIdx.z,
            A, lda, sA, B, ldb, sB, bias, sBias,
            Cv, ldc, sC, K, Mstore, outMode, Cv2, ldc2, sC2, ysplit);
}

// ===================== normalize df rows -> dfn (fp8), batched over scales =====================
__global__ __launch_bounds__(256) void norm_kernel(const f16* __restrict__ dfh,
                                                   unsigned* __restrict__ drec8, int N, int Mp)
{
  int wv = threadIdx.x >> 6, lane = threadIdx.x & 63;
  int node = blockIdx.x * 4 + wv;
  if (node >= N) return;
  int s = blockIdx.y;
  float4 d = ld4h(dfh + (size_t)s * Mp * 256 + (size_t)node * 256 + lane * 4);
  float ss = d.x * d.x + d.y * d.y + d.z * d.z + d.w * d.w;
  ss += __shfl_xor(ss, 1);  ss += __shfl_xor(ss, 2);  ss += __shfl_xor(ss, 4);
  ss += __shfl_xor(ss, 8);  ss += __shfl_xor(ss, 16); ss += __shfl_xor(ss, 32);
  float rn = 1.0f / fmaxf(sqrtf(ss), 1e-8f);
  drec8[(size_t)s * Mp * 64 + node * 64 + lane] = enc_fp8x4(d.x * rn, d.y * rn, d.z * rn, d.w * rn);
}

// ===================== edge attention: wave/node, slot(4) x sub(16), erec 1-ahead prefetch =====
__global__ __launch_bounds__(256) void edge_attn(
    const f16* __restrict__ nrec0, const unsigned* __restrict__ krec0,
    const unsigned* __restrict__ drec0, const int2* __restrict__ erec,
    const int* __restrict__ dptr, const int* __restrict__ perm,
    const float* __restrict__ enc_tab, const float* __restrict__ temp,
    f16* __restrict__ aggc, int N, int Mp)
{
  int wv = threadIdx.x >> 6, lane = threadIdx.x & 63;
  int node = blockIdx.x * 4 + wv;
  if (node >= N) return;
  node = perm[node];   // degree-descending schedule
  const int s = blockIdx.y;
  const int sshift = 7 * s;
  const f16* nrec = nrec0 + (size_t)s * Mp * 512;
  const unsigned* krec8 = krec0 + (size_t)s * Mp * 64;
  const unsigned* drec8 = drec0 + (size_t)s * Mp * 64;
  const float* enc_s = enc_tab + s * 1600;

  const int slot = lane >> 4;
  const int sub  = lane & 15;
  const int hd   = sub >> 1;
  const int half = sub & 1;
  const int doff = hd * 8 + half * 4;
  const int voff = hd * 32 + half * 16;

  float qf[16];
  {
    const f16* qp = nrec + (size_t)node * 512 + voff;
    f16x8 a = *(const f16x8*)qp;
    f16x8 b = *(const f16x8*)(qp + 8);
#pragma unroll
    for (int j = 0; j < 8; ++j) { qf[j] = (float)a[j]; qf[8 + j] = (float)b[j]; }
  }
  uint4 diw = *(const uint4*)(drec8 + node * 64 + doff);
  const float inv_th = 0.17677669529663687f / temp[s * 8 + hd];

  float m = -1e30f, z = 0.f;
  float acc[16];
#pragma unroll
  for (int i = 0; i < 16; ++i) acc[i] = 0.f;

  int e0 = dptr[node], e1 = dptr[node + 1];
  int nit = (e1 - e0 + 3) >> 2;
  if (nit > 0) {
    int ce = e0 + slot; if (ce >= e1) ce = e1 - 1;
    int2 recA = erec[ce];
    for (int it = 0; it < nit; ++it) {
      int en = e0 + (it + 1) * 4 + slot; en = (en < e1) ? en : e1 - 1;
      int2 recN = erec[en];

      int e = e0 + it * 4 + slot;
      bool valid = e < e1;
      int src = recA.x;
      unsigned pb = (unsigned)recA.y;
      uint4 kwv = *(const uint4*)(krec8 + src * 64 + doff);
      uint4 dwv = *(const uint4*)(drec8 + src * 64 + doff);
      const f16* vp = nrec + (size_t)src * 512 + 256 + voff;
      f16x8 vs0 = *(const f16x8*)vp;
      f16x8 vs1 = *(const f16x8*)(vp + 8);
      float enc = enc_s[((pb >> sshift) & 127u) * 16 + (pb >> 21)];

      unsigned kw[4] = {kwv.x, kwv.y, kwv.z, kwv.w};
      unsigned dw[4] = {dwv.x, dwv.y, dwv.z, dwv.w};
      unsigned di[4] = {diw.x, diw.y, diw.z, diw.w};
      float qk0 = 0.f, qk1 = 0.f, ds0 = 0.f, ds1 = 0.f;
#pragma unroll
      for (int w = 0; w < 4; ++w) {
        float4 kf = dec_fp8x4(kw[w]);
        qk0 = fmaf(qf[w*4+0], kf.x, qk0);
        qk1 = fmaf(qf[w*4+1], kf.y, qk1);
        qk0 = fmaf(qf[w*4+2], kf.z, qk0);
        qk1 = fmaf(qf[w*4+3], kf.w, qk1);
        float4 df = dec_fp8x4(dw[w]);
        float4 dd = dec_fp8x4(di[w]);
        ds0 = fmaf(dd.x, df.x, ds0);
        ds1 = fmaf(dd.y, df.y, ds1);
        ds0 = fmaf(dd.z, df.z, ds0);
        ds1 = fmaf(dd.w, df.w, ds1);
      }
      float qk = qk0 + qk1;
      float ds = ds0 + ds1;
      qk += __shfl_xor(qk, 1);
      ds += __shfl_xor(ds, 1); ds += __shfl_xor(ds, 2);
      ds += __shfl_xor(ds, 4); ds += __shfl_xor(ds, 8);

      float sc = (qk * inv_th + enc) * (1.0f + 0.5f * ds);
      sc = valid ? sc : -1e30f;
      if (__any(sc > m + 8.0f)) {
        float mn = fmaxf(m, sc);
        float rs = __expf(m - mn);
        z *= rs;
#pragma unroll
        for (int i = 0; i < 16; ++i) acc[i] *= rs;
        m = mn;
      }
      float p = __expf(sc - m) * (valid ? 1.0f : 0.0f);
      z += p;
#pragma unroll
      for (int j = 0; j < 8; ++j) acc[j]     = fmaf(p, (float)vs0[j], acc[j]);
#pragma unroll
      for (int j = 0; j < 8; ++j) acc[8 + j] = fmaf(p, (float)vs1[j], acc[8 + j]);

      recA = recN;
    }
  }

  float M = m;
  M = fmaxf(M, __shfl_xor(M, 16));
  M = fmaxf(M, __shfl_xor(M, 32));
  float f = __expf(m - M);
  z *= f;
  z += __shfl_xor(z, 16); z += __shfl_xor(z, 32);
#pragma unroll
  for (int i = 0; i < 16; ++i) {
    float a = acc[i] * f;
    a += __shfl_xor(a, 16); a += __shfl_xor(a, 32);
    acc[i] = a;
  }
  float rz = 1.0f / (z + 1e-16f);
  if (slot == 0) {
    f16* op = aggc + (size_t)node * 768 + s * 256 + voff;
    f16x8 o0, o1;
#pragma unroll
    for (int j = 0; j < 8; ++j) { o0[j] = (f16)(acc[j] * rz); o1[j] = (f16)(acc[8 + j] * rz); }
    *(f16x8*)op = o0;
    *(f16x8*)(op + 8) = o1;
  }
}

// ===================== host launcher =====================
extern "C" void kernel_launch(void* const* d_in, const int* in_sizes, int n_in,
                              void* d_out, int out_size, void* d_ws, size_t ws_size,
                              hipStream_t stream)
{
  const float* x      = (const float*)d_in[0];
  const float* coords = (const float*)d_in[1];
  const int*   eidx   = (const int*)  d_in[2];
  const float* Wq   = (const float*)d_in[3];
  const float* Wk   = (const float*)d_in[4];
  const float* Wv   = (const float*)d_in[5];
  const float* Wo   = (const float*)d_in[6];
  const float* bo   = (const float*)d_in[7];
  const float* temp = (const float*)d_in[8];
  const float* dist_emb = (const float*)d_in[9];
  const float* dir_emb  = (const float*)d_in[10];
  const float* Wsp1 = (const float*)d_in[11];
  const float* bsp1 = (const float*)d_in[12];
  const float* Wsp2 = (const float*)d_in[13];
  const float* bsp2 = (const float*)d_in[14];
  const float* Wd1  = (const float*)d_in[15];
  const float* bd1  = (const float*)d_in[16];
  const float* Wd2  = (const float*)d_in[17];
  const float* bd2  = (const float*)d_in[18];
  const float* Wf   = (const float*)d_in[19];
  const float* bf   = (const float*)d_in[20];
  (void)n_in; (void)out_size; (void)ws_size;

  const int N  = in_sizes[0] / 256;
  const int E  = in_sizes[2] / 2;
  const int Mp = ((N + 127) / 128) * 128;

  char* p = (char*)d_ws;
  auto alloc = [&](size_t b) -> void* {
    void* r = (void*)p;
    p += (b + 255) & ~(size_t)255;
    return r;
  };

  f16*      x_h   = (f16*)     alloc((size_t)Mp * 256 * 2);
  unsigned* x8    = (unsigned*)alloc((size_t)Mp * 256);
  f16*      nrec3 = (f16*)     alloc((size_t)3 * Mp * 512 * 2);
  unsigned* krec3 = (unsigned*)alloc((size_t)3 * Mp * 256);
  unsigned* drec3 = (unsigned*)alloc((size_t)3 * Mp * 256);
  f16*      dfh3  = (f16*)     alloc((size_t)3 * Mp * 256 * 2);
  f16*      aggc  = (f16*)     alloc((size_t)Mp * 768 * 2);
  f16*      wqvk  = (f16*)     alloc((size_t)3 * 768 * 256 * 2);
  f16*      wfo   = (f16*)     alloc((size_t)256 * 768 * 2);
  float*    bias_f = (float*)  alloc(256 * 4);
  f16*      wd2h  = (f16*)     alloc((size_t)3 * 256 * 128 * 2);
  float*    enc_tab = (float*) alloc((size_t)3 * 1600 * 4);
  int*    dptr = (int*)   alloc((size_t)(N + 1) * 4);
  int*    sptr = (int*)   alloc((size_t)(N + 1) * 4);
  int*    cptr = (int*)   alloc((size_t)401 * 4);
  int*    perm = (int*)   alloc((size_t)N * 4);
  int2*   erec = (int2*)  alloc((size_t)E * 8);
  int*    sdst = (int*)   alloc((size_t)E * 4);
  float2* scoord = (float2*)alloc((size_t)N * 8);
  float*  fvar = (float*) alloc((size_t)N * 4);
  int*    sp_i = (int*)   alloc((size_t)N * 4);
  float*  maxf = (float*) alloc(4 * 4);
  // ---- zeroed-every-call block ----
  char* z0 = p;
  int* deg_i   = (int*)alloc((size_t)N * 4);
  int* indeg_i = (int*)alloc((size_t)N * 4);
  int* fill_d  = (int*)alloc((size_t)N * 4);
  int* fill_s  = (int*)alloc((size_t)N * 4);
  int* cellcnt = (int*)alloc(400 * 4);
  int* fill_c  = (int*)alloc(400 * 4);
  size_t zbytes = (size_t)(p - z0);
  hipMemsetAsync(z0, 0, zbytes, stream);

  const int hb = (E + 255) / 256;
  // 1. prep: cast + enc tables + histograms + Wfo(tiled) + fused bias
  prep_kernel<<<2067 + hb + 96 + 1, 256, 0, stream>>>(
      x, Wq, Wk, Wv, Wd2, x_h, x8, wqvk, wd2h,
      dist_emb, dir_emb, Wsp1, bsp1, Wsp2, bsp2, enc_tab,
      eidx, coords, deg_i, indeg_i, cellcnt,
      Wf, Wo, bo, bf, wfo, bias_f, E, N, hb);
  // 2. scans + degree-desc perm
  scan_kernel<<<4, 1024, 0, stream>>>(indeg_i, deg_i, cellcnt, dptr, sptr, cptr, perm, N);
  // 3. CSR scatter + edge bins + cell scatter
  scatter_kernel<<<(E + 255) / 256, 256, 0, stream>>>(eidx, coords, dptr, sptr, cptr,
                                                      fill_d, fill_s, fill_c, erec, sdst, scoord, E, N);
  const int mtiles = Mp / 128;
  const int qkvB = mtiles * 18;
  // 4. mid: qkv GEMM (dep: prep) overlapped with node_stats (dep: scatter)
  mid_kernel<<<qkvB + (N + 3) / 4, 256, 0, stream>>>(
      x_h, wqvk, nrec3, (unsigned char*)krec3,
      coords, scoord, cptr, x, x8, sptr, sdst, sp_i, fvar,
      N, Mp, mtiles, qkvB);
  // 5. maxes
  maxred_kernel<<<1, 1024, 0, stream>>>(sptr, sp_i, fvar, maxf, N);
  // 6. fused density GEMM (h computed on the fly), all scales
  gemm_wd2<<<dim3(mtiles, 2, 3), 256, 0, stream>>>(sptr, sp_i, fvar, maxf, Wd1, bd1,
                                                   wd2h, bd2, dfh3, N, Mp);
  // 7. normalize -> fp8 dfn, all scales
  norm_kernel<<<dim3((N + 3) / 4, 3), 256, 0, stream>>>(dfh3, drec3, N, Mp);
  // 8. edge attention + scatter softmax + aggregate (slot4 x sub16, prefetched)
  edge_attn<<<dim3((N + 3) / 4, 3), 256, 0, stream>>>(nrec3, krec3, drec3, erec, dptr, perm,
                                                      enc_tab, temp, aggc, N, Mp);
  // 9. fused (Wo then Wf) GEMM -> d_out f32
  gemm_bt_f16<<<dim3(mtiles, 2, 1), 256, 0, stream>>>(aggc, 768, 0,
                                                      wfo, 768, 0, bias_f, 0,
                                                      d_out, 256, 0, 768, N, 0,
                                                      nullptr, 0, 0, 99);
}